// Round 6
// baseline (646.131 us; speedup 1.0000x reference)
//
#include <hip/hip_runtime.h>

#define LL 96
#define TT 24
#define HH 64
#define CC 8
#define GG 256   // 4*H
#define BT 4     // batches per block
#define NB 1024  // 4096/BT

typedef unsigned short u16t;
typedef unsigned int   u32t;
typedef __attribute__((ext_vector_type(8))) short bf16x8;
typedef __attribute__((ext_vector_type(4))) float f32x4;

__device__ __forceinline__ float b2f(u16t u){ union{u32t i; float f;} v; v.i=((u32t)u)<<16; return v.f; }
__device__ __forceinline__ float lo2f(u32t p){ union{u32t i; float f;} v; v.i=p<<16; return v.f; }
__device__ __forceinline__ float hi2f(u32t p){ union{u32t i; float f;} v; v.i=p&0xffff0000u; return v.f; }
__device__ __forceinline__ u16t f2b(float f){ union{float f; u32t i;} v; v.f=f; u32t l=(v.i>>16)&1u; v.i+=0x7fffu+l; return (u16t)(v.i>>16); }
__device__ __forceinline__ float sigm(float x){ return 1.f/(1.f+__expf(-x)); }
__device__ __forceinline__ float tanhx(float x){ float ax=fabsf(x); float e=__expf(-2.f*ax); float t=(1.f-e)/(1.f+e); return x<0.f? -t : t; }
__device__ __forceinline__ void up8(uint4 p, float* w){
    w[0]=lo2f(p.x); w[1]=hi2f(p.x); w[2]=lo2f(p.y); w[3]=hi2f(p.y);
    w[4]=lo2f(p.z); w[5]=hi2f(p.z); w[6]=lo2f(p.w); w[7]=hi2f(p.w);
}
__device__ __forceinline__ u32t pk2(float a, float b){ return (u32t)f2b(a) | ((u32t)f2b(b)<<16); }
__device__ __forceinline__ bf16x8 u2b8(uint4 u){ union{uint4 a; bf16x8 b;} v; v.a=u; return v.b; }
// A-layout slot for element (k local 0..63, m): [kb][quad][m=16][x=8] shorts
__device__ __forceinline__ int aaddr(int k, int m){ return (((k>>5)*4 + ((k>>3)&3))*16 + m)*8 + (k&7); }

// ---- dtype-agnostic load/store helpers --------------------------------------
template<bool F32> __device__ __forceinline__ float ldf(const void* p, size_t i){
    if constexpr (F32) return ((const float*)p)[i];
    else               return b2f(((const u16t*)p)[i]);
}
template<bool F32> __device__ __forceinline__ uint4 ld8p(const void* p, size_t i){
    if constexpr (F32){
        const float* f = (const float*)p + i;
        uint4 r; r.x = pk2(f[0],f[1]); r.y = pk2(f[2],f[3]);
                 r.z = pk2(f[4],f[5]); r.w = pk2(f[6],f[7]);
        return r;
    } else return *(const uint4*)((const u16t*)p + i);
}
template<bool F32> __device__ __forceinline__ u32t ld2p(const void* p, size_t i){
    if constexpr (F32){ const float* f = (const float*)p + i; return pk2(f[0],f[1]); }
    else return *(const u32t*)((const u16t*)p + i);
}
template<bool F32> __device__ __forceinline__ void stf(void* p, size_t i, float v){
    if constexpr (F32) ((float*)p)[i] = v;
    else               ((u16t*)p)[i] = f2b(v);
}
// encoder combined weight: k<8 -> Wih[r][k], k<72 -> Whh[r][k-8], else 0 (pad)
template<bool F32> __device__ __forceinline__ float ldW_enc(const void* wih, const void* whh, int r, int k){
    if (k < CC)      return ldf<F32>(wih, (size_t)r*CC + k);
    else if (k < 72) return ldf<F32>(whh, (size_t)r*HH + (k-CC));
    else             return 0.f;
}

// dtype probe (R5 FETCH_SIZE says bf16 is live; probe kept as cheap insurance)
__device__ __forceinline__ bool inputs_are_f32(const void* bih){
    const u16t* p = (const u16t*)bih;
    int cnt = 0;
    #pragma unroll
    for (int i = 0; i < 64; ++i){
        u32t e = ((u32t)p[i] >> 7) & 0xFFu;
        cnt += (e >= 128u) ? 1 : 0;
    }
    return cnt > 0;
}

// Fused: MFMA encoder (96 LSTM steps, 1 barrier/step via A ping-pong) +
// MFMA attention decoder (24 steps). BT=4 -> ~74.5 KB LDS -> 2 blocks/CU.
template<bool F32>
__global__ __launch_bounds__(256,2) void fused_kernel(
    const void* __restrict__ x_enc,
    const void* __restrict__ eWih, const void* __restrict__ eWhh,
    const void* __restrict__ ebih, const void* __restrict__ ebhh,
    const void* __restrict__ embW, const void* __restrict__ embb,
    const void* __restrict__ attnW, const void* __restrict__ attnb,
    const void* __restrict__ combW, const void* __restrict__ combb,
    const void* __restrict__ dWih, const void* __restrict__ dWhh,
    const void* __restrict__ dbih, const void* __restrict__ dbhh,
    const void* __restrict__ outW, const void* __restrict__ outb,
    void* __restrict__ outp)
{
    if (inputs_are_f32(ebih) != F32) return;   // self-disable wrong-dtype variant

    __shared__ __align__(16) u16t  eo[LL*BT*HH];   // [l][b][h] bf16, 48 KB
    __shared__ __align__(16) float slp[CC*10];     // seq_last [i][b]
    __shared__ __align__(16) short Abuf2[2][1536]; // enc A operand ping-pong, 6 KB
    __shared__ __align__(16) char  uni[20640];     // decoder scratch

    const int tid = threadIdx.x;
    const int b0  = blockIdx.x * BT;
    const int col = tid & 15, quad = (tid >> 4) & 3, wv = tid >> 6;

    // ---------------- encoder: B-fragments + bias in registers ----------------
    bf16x8 Bf[4][3];
    float  biasg[4];
    #pragma unroll
    for (int g = 0; g < 4; ++g){
        int r = g*64 + wv*16 + col;
        biasg[g] = ldf<F32>(ebih, r) + ldf<F32>(ebhh, r);
        #pragma unroll
        for (int kb = 0; kb < 3; ++kb){
            bf16x8 v;
            #pragma unroll
            for (int x = 0; x < 8; ++x){
                int k = kb*32 + quad*8 + x;
                v[x] = (short)f2b(ldW_enc<F32>(eWih, eWhh, r, k));
            }
            Bf[g][kb] = v;
        }
    }
    for (int n = tid; n < 2*1536; n += 256) ((short*)Abuf2)[n] = 0;
    float sl = 0.f; size_t xbase = 0;
    if (tid < BT*CC){ int b = tid >> 3, i = tid & 7;
        xbase = (size_t)(b0+b)*(LL*CC) + i;
        sl = ldf<F32>(x_enc, xbase + (size_t)(LL-1)*CC);
        slp[i*10 + b] = sl; }
    __syncthreads();
    if (tid < BT*CC) Abuf2[0][tid] = (short)f2b(ldf<F32>(x_enc, xbase) - sl);  // x(0)
    float xr = (tid < BT*CC) ? ldf<F32>(x_enc, xbase + CC) : 0.f;              // prefetch x(1)

    const int jmy = wv*16 + col;
    const int kh  = 8 + jmy;
    const int hwbase = ((kh>>5)*64 + ((kh>>3)&3)*16)*8 + (kh&7);

    float creg[4] = {0.f,0.f,0.f,0.f};
    float hfin[4] = {0.f,0.f,0.f,0.f};
    u16t  hb16[4] = {0,0,0,0};

    for (int t = 0; t < LL; ++t){
        __syncthreads();                           // AbR writes (x(t), h(t-1)) visible
        const bf16x8* AbR = (const bf16x8*)Abuf2[t & 1];
        short*        AbW = Abuf2[(t + 1) & 1];
        bf16x8 a0 = AbR[(0*4 + quad)*16 + col];
        bf16x8 a1 = AbR[(1*4 + quad)*16 + col];
        bf16x8 a2 = AbR[(2*4 + quad)*16 + col];
        f32x4 acc[4];
        #pragma unroll
        for (int g = 0; g < 4; ++g){
            f32x4 a; a[0]=biasg[g]; a[1]=biasg[g]; a[2]=biasg[g]; a[3]=biasg[g];
            a = __builtin_amdgcn_mfma_f32_16x16x32_bf16(a0, Bf[g][0], a, 0,0,0);
            a = __builtin_amdgcn_mfma_f32_16x16x32_bf16(a1, Bf[g][1], a, 0,0,0);
            a = __builtin_amdgcn_mfma_f32_16x16x32_bf16(a2, Bf[g][2], a, 0,0,0);
            acc[g] = a;
        }
        // C/D row = quad*4+reg = batch; BT=4 -> only quad==0 rows live
        if (quad == 0){
            #pragma unroll
            for (int r = 0; r < 4; ++r){
                float c = sigm(acc[1][r])*creg[r] + sigm(acc[0][r])*tanhx(acc[2][r]);
                float h = sigm(acc[3][r])*tanhx(c);
                creg[r] = c; hfin[r] = h; hb16[r] = f2b(h);
                eo[((size_t)t*BT + r)*HH + jmy] = hb16[r];
                AbW[hwbase + r*8] = (short)hb16[r];        // h(t) -> next buffer
            }
        }
        if (tid < BT*CC && t < LL-1){
            AbW[tid] = (short)f2b(xr - sl);                // x(t+1) -> next buffer
            int tn = (t+2 < LL) ? t+2 : LL-1;
            xr = ldf<F32>(x_enc, xbase + (size_t)tn*CC);
        }
    }

    // ---------------- decoder weight fragments (registers) ----------------
    bf16x8 Bd[4][4];                      // dec LSTM: gate g, j-slice wv
    #pragma unroll
    for (int g = 0; g < 4; ++g){
        int r = g*64 + wv*16 + col;
        Bd[g][0] = u2b8(ld8p<F32>(dWih, (size_t)r*HH + quad*8));
        Bd[g][1] = u2b8(ld8p<F32>(dWih, (size_t)r*HH + 32 + quad*8));
        Bd[g][2] = u2b8(ld8p<F32>(dWhh, (size_t)r*HH + quad*8));
        Bd[g][3] = u2b8(ld8p<F32>(dWhh, (size_t)r*HH + 32 + quad*8));
    }
    bf16x8 Ba[2][4];                      // attn: l-tiles wv (+ 4+wv for wv<2)
    #pragma unroll
    for (int kb = 0; kb < 4; ++kb)
        Ba[0][kb] = u2b8(ld8p<F32>(attnW, (size_t)(wv*16+col)*128 + kb*32 + quad*8));
    if (wv < 2){
        #pragma unroll
        for (int kb = 0; kb < 4; ++kb)
            Ba[1][kb] = u2b8(ld8p<F32>(attnW, (size_t)((4+wv)*16+col)*128 + kb*32 + quad*8));
    } else {
        #pragma unroll
        for (int kb = 0; kb < 4; ++kb) Ba[1][kb] = Ba[0][kb];
    }
    bf16x8 Bc[4];                         // comb: h-tile wv
    #pragma unroll
    for (int kb = 0; kb < 4; ++kb)
        Bc[kb] = u2b8(ld8p<F32>(combW, (size_t)(wv*16+col)*128 + kb*32 + quad*8));
    u32t eR[4];                           // emb row h = tid&63
    { int h = tid & 63;
      #pragma unroll
      for (int g = 0; g < 4; ++g) eR[g] = ld2p<F32>(embW, (size_t)h*CC + g*2); }
    uint4 oR[8];                          // out row i (tid<32)
    if (tid < BT*CC){ int i = tid & 7;
        #pragma unroll
        for (int g = 0; g < 8; ++g) oR[g] = ld8p<F32>(outW, (size_t)i*HH + g*8); }

    // ---------------- decoder LDS views + init ----------------
    float* decB  = (float*)(uni + 0);      // 256 f
    float* attnB = (float*)(uni + 1024);   // 96 f
    float* embB  = (float*)(uni + 1408);   // 64 f
    float* combB = (float*)(uni + 1664);   // 64 f
    float* outB  = (float*)(uni + 1920);   // 8 f
    float* awv   = (float*)(uni + 1952);   // [l][8b] (b<4 used)
    float* Lg    = (float*)(uni + 5024);   // [l][8b] logits
    float* hdV   = (float*)(uni + 8096);   // [j][8b]
    float* predV = (float*)(uni + 10144);  // [i][8b]
    u16t*  Ae    = (u16t*)(uni + 10400);   // emb A-buf (k 0..63)
    u16t*  Ah0   = (u16t*)(uni + 12448);   // h A-buf ping
    u16t*  Ah1   = (u16t*)(uni + 14496);   // h A-buf pong
    u16t*  Actx  = (u16t*)(uni + 16544);   // ctx A-buf (k 64..127 of comb)
    u16t*  Acmb  = (u16t*)(uni + 18592);   // comb A-buf (k 0..63 of LSTM)

    // encoder -> decoder handoff: c stays in registers; h -> Ah0 + hdV
    if (quad == 0){
        #pragma unroll
        for (int r = 0; r < 4; ++r){
            hdV[jmy*8 + r]      = hfin[r];
            Ah0[aaddr(jmy, r)]  = hb16[r];
        }
    }
    decB[tid] = ldf<F32>(dbih, tid) + ldf<F32>(dbhh, tid);
    if (tid < LL) attnB[tid] = ldf<F32>(attnb, tid);
    if (tid < HH) embB[tid]  = ldf<F32>(embb, tid);
    if (tid < HH) combB[tid] = ldf<F32>(combb, tid);
    if (tid < CC) outB[tid]  = ldf<F32>(outb, tid);
    if (tid < 64) predV[tid] = 0.f;        // dec_in0 = x[:,-1]-seq_last = 0
    __syncthreads();

    const int hA  = tid & 63, bqA = tid >> 6;  // P1: 1 batch per thread
    const int bS  = tid >> 5, lgS = tid & 31;  // P2b/P3 (32-lane groups, bS<4 active)
    const bf16x8* AeV   = (const bf16x8*)Ae;
    const bf16x8* ActxV = (const bf16x8*)Actx;
    const bf16x8* AcmbV = (const bf16x8*)Acmb;

    for (int t = 0; t < TT; ++t){
        u16t* AhR = (t & 1) ? Ah1 : Ah0;
        u16t* AhW = (t & 1) ? Ah0 : Ah1;
        const bf16x8* AhV = (const bf16x8*)AhR;

        // P1: emb = relu(pred @ embW^T + b) -> Ae (bf16, A-layout); batch=bqA
        {
            float a0 = embB[hA];
            #pragma unroll
            for (int g = 0; g < 4; ++g){
                u32t p = eR[g];
                a0 += lo2f(p)*predV[(g*2)*8 + bqA] + hi2f(p)*predV[(g*2+1)*8 + bqA];
            }
            Ae[aaddr(hA, bqA)] = f2b(fmaxf(a0, 0.f));
        }
        __syncthreads();

        // P2a: attention logits via MFMA; wave wv -> l-tile(s) {wv, 4+wv}
        {
            bf16x8 ae0 = AeV[(0*4+quad)*16 + col], ae1 = AeV[(1*4+quad)*16 + col];
            bf16x8 ah0 = AhV[(0*4+quad)*16 + col], ah1 = AhV[(1*4+quad)*16 + col];
            const int ns = (wv < 2) ? 2 : 1;
            for (int s = 0; s < ns; ++s){
                int lt = (s == 0) ? wv : 4+wv;
                float bz = attnB[lt*16 + col];
                f32x4 a; a[0]=bz; a[1]=bz; a[2]=bz; a[3]=bz;
                a = __builtin_amdgcn_mfma_f32_16x16x32_bf16(ae0, Ba[s][0], a, 0,0,0);
                a = __builtin_amdgcn_mfma_f32_16x16x32_bf16(ae1, Ba[s][1], a, 0,0,0);
                a = __builtin_amdgcn_mfma_f32_16x16x32_bf16(ah0, Ba[s][2], a, 0,0,0);
                a = __builtin_amdgcn_mfma_f32_16x16x32_bf16(ah1, Ba[s][3], a, 0,0,0);
                if (quad == 0)
                    *(float4*)&Lg[(lt*16+col)*8] = make_float4(a[0],a[1],a[2],a[3]);
            }
        }
        __syncthreads();

        // P2b: softmax per batch (32-lane group == one batch; bS<4 active)
        if (bS < BT){
            int l = lgS*3;
            float ev0 = Lg[l*8 + bS], ev1 = Lg[(l+1)*8 + bS], ev2 = Lg[(l+2)*8 + bS];
            float mx = fmaxf(ev0, fmaxf(ev1, ev2));
            #pragma unroll
            for (int m = 16; m >= 1; m >>= 1) mx = fmaxf(mx, __shfl_xor(mx, m, 32));
            float e0 = __expf(ev0 - mx), e1 = __expf(ev1 - mx), e2 = __expf(ev2 - mx);
            float sm = e0 + e1 + e2;
            #pragma unroll
            for (int m = 16; m >= 1; m >>= 1) sm += __shfl_xor(sm, m, 32);
            float inv = 1.f / sm;
            awv[l*8 + bS]     = e0*inv;
            awv[(l+1)*8 + bS] = e1*inv;
            awv[(l+2)*8 + bS] = e2*inv;
        }
        // P3: ctx = sum_l aw[l] * eo[l,b,:] -> Actx. Same 32-lane group wrote
        // awv -> intra-wave LDS RAW, ordered by lgkmcnt; no barrier needed.
        if (bS < BT){
            int hh0 = lgS*2;
            float a0 = 0.f, a1 = 0.f;
            #pragma unroll 4
            for (int l = 0; l < LL; ++l){
                float av = awv[l*8 + bS];
                u32t p = *(const u32t*)&eo[((size_t)l*BT + bS)*HH + hh0];
                a0 += av*lo2f(p);
                a1 += av*hi2f(p);
            }
            Actx[aaddr(hh0,   bS)] = f2b(a0);
            Actx[aaddr(hh0+1, bS)] = f2b(a1);
        }
        __syncthreads();

        // P4: comb = [emb|ctx] @ combW^T + b via MFMA -> Acmb (bf16, A-layout)
        {
            bf16x8 ae0 = AeV[(0*4+quad)*16 + col],   ae1 = AeV[(1*4+quad)*16 + col];
            bf16x8 ax0 = ActxV[(0*4+quad)*16 + col], ax1 = ActxV[(1*4+quad)*16 + col];
            int h = wv*16 + col;
            float bz = combB[h];
            f32x4 a; a[0]=bz; a[1]=bz; a[2]=bz; a[3]=bz;
            a = __builtin_amdgcn_mfma_f32_16x16x32_bf16(ae0, Bc[0], a, 0,0,0);
            a = __builtin_amdgcn_mfma_f32_16x16x32_bf16(ae1, Bc[1], a, 0,0,0);
            a = __builtin_amdgcn_mfma_f32_16x16x32_bf16(ax0, Bc[2], a, 0,0,0);
            a = __builtin_amdgcn_mfma_f32_16x16x32_bf16(ax1, Bc[3], a, 0,0,0);
            if (quad == 0){
                #pragma unroll
                for (int r = 0; r < 4; ++r)
                    Acmb[aaddr(h, r)] = f2b(a[r]);
            }
        }
        __syncthreads();

        // P5: dec LSTM gates via MFMA (gate-permuted); in-register c update
        {
            bf16x8 ac0 = AcmbV[(0*4+quad)*16 + col], ac1 = AcmbV[(1*4+quad)*16 + col];
            bf16x8 ah0 = AhV[(0*4+quad)*16 + col],   ah1 = AhV[(1*4+quad)*16 + col];
            f32x4 g4[4];
            #pragma unroll
            for (int g = 0; g < 4; ++g){
                float bz = decB[g*64 + wv*16 + col];
                f32x4 a; a[0]=bz; a[1]=bz; a[2]=bz; a[3]=bz;
                a = __builtin_amdgcn_mfma_f32_16x16x32_bf16(ac0, Bd[g][0], a, 0,0,0);
                a = __builtin_amdgcn_mfma_f32_16x16x32_bf16(ac1, Bd[g][1], a, 0,0,0);
                a = __builtin_amdgcn_mfma_f32_16x16x32_bf16(ah0, Bd[g][2], a, 0,0,0);
                a = __builtin_amdgcn_mfma_f32_16x16x32_bf16(ah1, Bd[g][3], a, 0,0,0);
                g4[g] = a;
            }
            if (quad == 0){
                #pragma unroll
                for (int r = 0; r < 4; ++r){
                    float c = sigm(g4[1][r])*creg[r] + sigm(g4[0][r])*tanhx(g4[2][r]);
                    float h = sigm(g4[3][r])*tanhx(c);
                    creg[r] = c;
                    hdV[jmy*8 + r]     = h;
                    AhW[aaddr(jmy, r)] = f2b(h);
                }
            }
        }
        __syncthreads();

        // P7: pred = h @ outW^T + b; emit output (+seq_last); feed back
        if (tid < BT*CC){
            int i = tid & 7, b = tid >> 3;
            float a = outB[i];
            #pragma unroll
            for (int g = 0; g < 8; ++g){
                float w[8]; up8(oR[g], w);
                #pragma unroll
                for (int q = 0; q < 8; ++q) a += w[q]*hdV[(g*8+q)*8 + b];
            }
            predV[i*8 + b] = a;
            stf<F32>(outp, ((size_t)(b0+b)*TT + t)*CC + i, a + slp[i*10 + b]);
        }
        __syncthreads();
    }
}

// --------------------------------------------------------------- launch -----
extern "C" void kernel_launch(void* const* d_in, const int* in_sizes, int n_in,
                              void* d_out, int out_size, void* d_ws, size_t ws_size,
                              hipStream_t stream)
{
    (void)in_sizes; (void)n_in; (void)d_ws; (void)ws_size; (void)out_size;
    fused_kernel<false><<<NB, 256, 0, stream>>>(
        d_in[0],
        d_in[4],  d_in[5],  d_in[6],  d_in[7],
        d_in[8],  d_in[9],  d_in[10], d_in[11],
        d_in[12], d_in[13], d_in[14], d_in[15],
        d_in[16], d_in[17], d_in[18], d_in[19],
        d_out);
    fused_kernel<true><<<NB, 256, 0, stream>>>(
        d_in[0],
        d_in[4],  d_in[5],  d_in[6],  d_in[7],
        d_in[8],  d_in[9],  d_in[10], d_in[11],
        d_in[12], d_in[13], d_in[14], d_in[15],
        d_in[16], d_in[17], d_in[18], d_in[19],
        d_out);
}

// Round 7
// 426.212 us; speedup vs baseline: 1.5160x; 1.5160x over previous
//
#include <hip/hip_runtime.h>

#define LL 96
#define TT 24
#define HH 64
#define CC 8
#define GG 256   // 4*H
#define BT 8     // batches per block
#define NB 512   // 4096/BT

typedef unsigned short u16t;
typedef unsigned int   u32t;
typedef unsigned char  u8t;
typedef __attribute__((ext_vector_type(8))) short bf16x8;
typedef __attribute__((ext_vector_type(4))) float f32x4;

__device__ __forceinline__ float b2f(u16t u){ union{u32t i; float f;} v; v.i=((u32t)u)<<16; return v.f; }
__device__ __forceinline__ float lo2f(u32t p){ union{u32t i; float f;} v; v.i=p<<16; return v.f; }
__device__ __forceinline__ float hi2f(u32t p){ union{u32t i; float f;} v; v.i=p&0xffff0000u; return v.f; }
__device__ __forceinline__ u16t f2b(float f){ union{float f; u32t i;} v; v.f=f; u32t l=(v.i>>16)&1u; v.i+=0x7fffu+l; return (u16t)(v.i>>16); }
__device__ __forceinline__ float sigm(float x){ return 1.f/(1.f+__expf(-x)); }
__device__ __forceinline__ float tanhx(float x){ float ax=fabsf(x); float e=__expf(-2.f*ax); float t=(1.f-e)/(1.f+e); return x<0.f? -t : t; }
__device__ __forceinline__ void up8(uint4 p, float* w){
    w[0]=lo2f(p.x); w[1]=hi2f(p.x); w[2]=lo2f(p.y); w[3]=hi2f(p.y);
    w[4]=lo2f(p.z); w[5]=hi2f(p.z); w[6]=lo2f(p.w); w[7]=hi2f(p.w);
}
__device__ __forceinline__ u32t pk2(float a, float b){ return (u32t)f2b(a) | ((u32t)f2b(b)<<16); }
__device__ __forceinline__ bf16x8 u2b8(uint4 u){ union{uint4 a; bf16x8 b;} v; v.a=u; return v.b; }
// A-layout slot for element (k local 0..63, m): [kb][quad][m=16][x=8] shorts
__device__ __forceinline__ int aaddr(int k, int m){ return (((k>>5)*4 + ((k>>3)&3))*16 + m)*8 + (k&7); }

// ---- fp8 e5m2 (= truncated fp16) helpers -----------------------------------
__device__ __forceinline__ u8t f2e5(float f){
    _Float16 h = (_Float16)f;                    // RNE f32->f16 (v_cvt_f16_f32)
    u16t u; __builtin_memcpy(&u, &h, 2);
    u16t r = (u16t)(u + 0xFFu + ((u >> 8) & 1u)); // RNE to 2-bit mantissa
    return (u8t)(r >> 8);
}
__device__ __forceinline__ float e52f(u32t b){   // low 8 bits used
    u16t u = (u16t)(b << 8);
    _Float16 h; __builtin_memcpy(&h, &u, 2);
    return (float)h;                             // v_cvt_f32_f16
}

// ---- dtype-agnostic load/store helpers --------------------------------------
template<bool F32> __device__ __forceinline__ float ldf(const void* p, size_t i){
    if constexpr (F32) return ((const float*)p)[i];
    else               return b2f(((const u16t*)p)[i]);
}
template<bool F32> __device__ __forceinline__ uint4 ld8p(const void* p, size_t i){
    if constexpr (F32){
        const float* f = (const float*)p + i;
        uint4 r; r.x = pk2(f[0],f[1]); r.y = pk2(f[2],f[3]);
                 r.z = pk2(f[4],f[5]); r.w = pk2(f[6],f[7]);
        return r;
    } else return *(const uint4*)((const u16t*)p + i);
}
template<bool F32> __device__ __forceinline__ u32t ld2p(const void* p, size_t i){
    if constexpr (F32){ const float* f = (const float*)p + i; return pk2(f[0],f[1]); }
    else return *(const u32t*)((const u16t*)p + i);
}
template<bool F32> __device__ __forceinline__ void stf(void* p, size_t i, float v){
    if constexpr (F32) ((float*)p)[i] = v;
    else               ((u16t*)p)[i] = f2b(v);
}
// encoder combined weight: k<8 -> Wih[r][k], k<72 -> Whh[r][k-8], else 0 (pad)
template<bool F32> __device__ __forceinline__ float ldW_enc(const void* wih, const void* whh, int r, int k){
    if (k < CC)      return ldf<F32>(wih, (size_t)r*CC + k);
    else if (k < 72) return ldf<F32>(whh, (size_t)r*HH + (k-CC));
    else             return 0.f;
}

// dtype probe (bf16 confirmed live by R5 FETCH_SIZE; kept as cheap insurance)
__device__ __forceinline__ bool inputs_are_f32(const void* bih){
    const u16t* p = (const u16t*)bih;
    int cnt = 0;
    #pragma unroll
    for (int i = 0; i < 64; ++i){
        u32t e = ((u32t)p[i] >> 7) & 0xFFu;
        cnt += (e >= 128u) ? 1 : 0;
    }
    return cnt > 0;
}

// Fused: MFMA encoder (96 LSTM steps, 1 barrier/step via A ping-pong) +
// MFMA attention decoder (24 steps). BT=8, eo in fp8 e5m2 -> ~76 KB LDS
// -> 2 blocks/CU with R5's per-block work (R6 lesson: never shrink BT).
template<bool F32>
__global__ __launch_bounds__(256,2) void fused_kernel(
    const void* __restrict__ x_enc,
    const void* __restrict__ eWih, const void* __restrict__ eWhh,
    const void* __restrict__ ebih, const void* __restrict__ ebhh,
    const void* __restrict__ embW, const void* __restrict__ embb,
    const void* __restrict__ attnW, const void* __restrict__ attnb,
    const void* __restrict__ combW, const void* __restrict__ combb,
    const void* __restrict__ dWih, const void* __restrict__ dWhh,
    const void* __restrict__ dbih, const void* __restrict__ dbhh,
    const void* __restrict__ outW, const void* __restrict__ outb,
    void* __restrict__ outp)
{
    if (inputs_are_f32(ebih) != F32) return;   // self-disable wrong-dtype variant

    __shared__ __align__(16) u8t   eo[LL*BT*HH];   // [l][b][h] fp8 e5m2, 48 KB
    __shared__ __align__(16) float slp[CC*10];     // seq_last [i][b]
    __shared__ __align__(16) short Abuf2[2][1536]; // enc A operand ping-pong, 6 KB
    __shared__ __align__(16) char  uni[20640];     // decoder scratch

    const int tid = threadIdx.x;
    const int b0  = blockIdx.x * BT;
    const int col = tid & 15, quad = (tid >> 4) & 3, wv = tid >> 6;

    // ---------------- encoder: B-fragments + bias in registers ----------------
    bf16x8 Bf[4][3];
    float  biasg[4];
    #pragma unroll
    for (int g = 0; g < 4; ++g){
        int r = g*64 + wv*16 + col;
        biasg[g] = ldf<F32>(ebih, r) + ldf<F32>(ebhh, r);
        #pragma unroll
        for (int kb = 0; kb < 3; ++kb){
            bf16x8 v;
            #pragma unroll
            for (int x = 0; x < 8; ++x){
                int k = kb*32 + quad*8 + x;
                v[x] = (short)f2b(ldW_enc<F32>(eWih, eWhh, r, k));
            }
            Bf[g][kb] = v;
        }
    }
    for (int n = tid; n < 2*1536; n += 256) ((short*)Abuf2)[n] = 0;
    float sl = 0.f; size_t xbase = 0;
    if (tid < BT*CC){ int b = tid >> 3, i = tid & 7;
        xbase = (size_t)(b0+b)*(LL*CC) + i;
        sl = ldf<F32>(x_enc, xbase + (size_t)(LL-1)*CC);
        slp[i*10 + b] = sl; }
    __syncthreads();
    if (tid < BT*CC) Abuf2[0][tid] = (short)f2b(ldf<F32>(x_enc, xbase) - sl);  // x(0)
    float xr = (tid < BT*CC) ? ldf<F32>(x_enc, xbase + CC) : 0.f;              // prefetch x(1)

    const int jmy = wv*16 + col;
    const int kh  = 8 + jmy;
    const int hwbase = ((kh>>5)*64 + ((kh>>3)&3)*16)*8 + (kh&7);

    float creg[4] = {0.f,0.f,0.f,0.f};
    float hfin[4] = {0.f,0.f,0.f,0.f};
    u16t  hb16[4] = {0,0,0,0};

    for (int t = 0; t < LL; ++t){
        __syncthreads();                           // AbR writes (x(t), h(t-1)) visible
        const bf16x8* AbR = (const bf16x8*)Abuf2[t & 1];
        short*        AbW = Abuf2[(t + 1) & 1];
        bf16x8 a0 = AbR[(0*4 + quad)*16 + col];
        bf16x8 a1 = AbR[(1*4 + quad)*16 + col];
        bf16x8 a2 = AbR[(2*4 + quad)*16 + col];
        f32x4 acc[4];
        #pragma unroll
        for (int g = 0; g < 4; ++g){
            f32x4 a; a[0]=biasg[g]; a[1]=biasg[g]; a[2]=biasg[g]; a[3]=biasg[g];
            a = __builtin_amdgcn_mfma_f32_16x16x32_bf16(a0, Bf[g][0], a, 0,0,0);
            a = __builtin_amdgcn_mfma_f32_16x16x32_bf16(a1, Bf[g][1], a, 0,0,0);
            a = __builtin_amdgcn_mfma_f32_16x16x32_bf16(a2, Bf[g][2], a, 0,0,0);
            acc[g] = a;
        }
        // C/D row = quad*4+reg = batch; BT=8 -> quad<2 rows live
        if (quad < 2){
            #pragma unroll
            for (int r = 0; r < 4; ++r){
                int b = quad*4 + r;
                float c = sigm(acc[1][r])*creg[r] + sigm(acc[0][r])*tanhx(acc[2][r]);
                float h = sigm(acc[3][r])*tanhx(c);
                creg[r] = c; hfin[r] = h; hb16[r] = f2b(h);
                eo[((size_t)t*BT + b)*HH + jmy] = f2e5(h);
                AbW[hwbase + b*8] = (short)hb16[r];        // h(t) -> next buffer
            }
        }
        if (tid < BT*CC && t < LL-1){
            AbW[tid] = (short)f2b(xr - sl);                // x(t+1) -> next buffer
            int tn = (t+2 < LL) ? t+2 : LL-1;
            xr = ldf<F32>(x_enc, xbase + (size_t)tn*CC);
        }
    }

    // ---------------- decoder weight fragments (registers) ----------------
    bf16x8 Bd[4][4];                      // dec LSTM: gate g, j-slice wv
    #pragma unroll
    for (int g = 0; g < 4; ++g){
        int r = g*64 + wv*16 + col;
        Bd[g][0] = u2b8(ld8p<F32>(dWih, (size_t)r*HH + quad*8));
        Bd[g][1] = u2b8(ld8p<F32>(dWih, (size_t)r*HH + 32 + quad*8));
        Bd[g][2] = u2b8(ld8p<F32>(dWhh, (size_t)r*HH + quad*8));
        Bd[g][3] = u2b8(ld8p<F32>(dWhh, (size_t)r*HH + 32 + quad*8));
    }
    bf16x8 Ba[2][4];                      // attn: l-tiles wv (+ 4+wv for wv<2)
    #pragma unroll
    for (int kb = 0; kb < 4; ++kb)
        Ba[0][kb] = u2b8(ld8p<F32>(attnW, (size_t)(wv*16+col)*128 + kb*32 + quad*8));
    if (wv < 2){
        #pragma unroll
        for (int kb = 0; kb < 4; ++kb)
            Ba[1][kb] = u2b8(ld8p<F32>(attnW, (size_t)((4+wv)*16+col)*128 + kb*32 + quad*8));
    } else {
        #pragma unroll
        for (int kb = 0; kb < 4; ++kb) Ba[1][kb] = Ba[0][kb];
    }
    bf16x8 Bc[4];                         // comb: h-tile wv
    #pragma unroll
    for (int kb = 0; kb < 4; ++kb)
        Bc[kb] = u2b8(ld8p<F32>(combW, (size_t)(wv*16+col)*128 + kb*32 + quad*8));
    u32t eR[4];                           // emb row h = tid&63
    { int h = tid & 63;
      #pragma unroll
      for (int g = 0; g < 4; ++g) eR[g] = ld2p<F32>(embW, (size_t)h*CC + g*2); }
    uint4 oR[8];                          // out row i (tid<64)
    if (tid < BT*CC){ int i = tid & 7;
        #pragma unroll
        for (int g = 0; g < 8; ++g) oR[g] = ld8p<F32>(outW, (size_t)i*HH + g*8); }

    // ---------------- decoder LDS views + init ----------------
    float* decB  = (float*)(uni + 0);      // 256 f
    float* attnB = (float*)(uni + 1024);   // 96 f
    float* embB  = (float*)(uni + 1408);   // 64 f
    float* combB = (float*)(uni + 1664);   // 64 f
    float* outB  = (float*)(uni + 1920);   // 8 f
    float* awv   = (float*)(uni + 1952);   // [l][8b]
    float* Lg    = (float*)(uni + 5024);   // [l][8b] logits
    float* hdV   = (float*)(uni + 8096);   // [j][8b]
    float* predV = (float*)(uni + 10144);  // [i][8b]
    u16t*  Ae    = (u16t*)(uni + 10400);   // emb A-buf (k 0..63)
    u16t*  Ah0   = (u16t*)(uni + 12448);   // h A-buf ping
    u16t*  Ah1   = (u16t*)(uni + 14496);   // h A-buf pong
    u16t*  Actx  = (u16t*)(uni + 16544);   // ctx A-buf (k 64..127 of comb)
    u16t*  Acmb  = (u16t*)(uni + 18592);   // comb A-buf (k 0..63 of LSTM)

    // encoder -> decoder handoff: c stays in registers; h -> Ah0 + hdV
    if (quad < 2){
        #pragma unroll
        for (int r = 0; r < 4; ++r){
            int b = quad*4 + r;
            hdV[jmy*8 + b]      = hfin[r];
            Ah0[aaddr(jmy, b)]  = hb16[r];
        }
    }
    decB[tid] = ldf<F32>(dbih, tid) + ldf<F32>(dbhh, tid);
    if (tid < LL) attnB[tid] = ldf<F32>(attnb, tid);
    if (tid < HH) embB[tid]  = ldf<F32>(embb, tid);
    if (tid < HH) combB[tid] = ldf<F32>(combb, tid);
    if (tid < CC) outB[tid]  = ldf<F32>(outb, tid);
    if (tid < 64) predV[tid] = 0.f;        // dec_in0 = x[:,-1]-seq_last = 0
    __syncthreads();

    const int hA  = tid & 63, bqA = tid >> 6;  // P1
    const int bS  = tid >> 5, lgS = tid & 31;  // P2b/P3 (32-lane groups)
    const bf16x8* AeV   = (const bf16x8*)Ae;
    const bf16x8* ActxV = (const bf16x8*)Actx;
    const bf16x8* AcmbV = (const bf16x8*)Acmb;

    for (int t = 0; t < TT; ++t){
        u16t* AhR = (t & 1) ? Ah1 : Ah0;
        u16t* AhW = (t & 1) ? Ah0 : Ah1;
        const bf16x8* AhV = (const bf16x8*)AhR;

        // P1: emb = relu(pred @ embW^T + b) -> Ae (bf16, A-layout)
        {
            int ba = bqA*2;
            float a0 = embB[hA], a1 = a0;
            #pragma unroll
            for (int g = 0; g < 4; ++g){
                u32t p = eR[g];
                float w0 = lo2f(p), w1 = hi2f(p);
                float2 pv0 = *(const float2*)&predV[(g*2)*8 + ba];
                float2 pv1 = *(const float2*)&predV[(g*2+1)*8 + ba];
                a0 += w0*pv0.x + w1*pv1.x;
                a1 += w0*pv0.y + w1*pv1.y;
            }
            Ae[aaddr(hA, ba)]   = f2b(fmaxf(a0, 0.f));
            Ae[aaddr(hA, ba+1)] = f2b(fmaxf(a1, 0.f));
        }
        __syncthreads();

        // P2a: attention logits via MFMA; wave wv -> l-tile(s) {wv, 4+wv}
        {
            bf16x8 ae0 = AeV[(0*4+quad)*16 + col], ae1 = AeV[(1*4+quad)*16 + col];
            bf16x8 ah0 = AhV[(0*4+quad)*16 + col], ah1 = AhV[(1*4+quad)*16 + col];
            const int ns = (wv < 2) ? 2 : 1;
            for (int s = 0; s < ns; ++s){
                int lt = (s == 0) ? wv : 4+wv;
                float bz = attnB[lt*16 + col];
                f32x4 a; a[0]=bz; a[1]=bz; a[2]=bz; a[3]=bz;
                a = __builtin_amdgcn_mfma_f32_16x16x32_bf16(ae0, Ba[s][0], a, 0,0,0);
                a = __builtin_amdgcn_mfma_f32_16x16x32_bf16(ae1, Ba[s][1], a, 0,0,0);
                a = __builtin_amdgcn_mfma_f32_16x16x32_bf16(ah0, Ba[s][2], a, 0,0,0);
                a = __builtin_amdgcn_mfma_f32_16x16x32_bf16(ah1, Ba[s][3], a, 0,0,0);
                if (quad < 2)
                    *(float4*)&Lg[(lt*16+col)*8 + quad*4] = make_float4(a[0],a[1],a[2],a[3]);
            }
        }
        __syncthreads();

        // P2b: softmax per batch (32-lane group == one batch)
        {
            int l = lgS*3;
            float ev0 = Lg[l*8 + bS], ev1 = Lg[(l+1)*8 + bS], ev2 = Lg[(l+2)*8 + bS];
            float mx = fmaxf(ev0, fmaxf(ev1, ev2));
            #pragma unroll
            for (int m = 16; m >= 1; m >>= 1) mx = fmaxf(mx, __shfl_xor(mx, m, 32));
            float e0 = __expf(ev0 - mx), e1 = __expf(ev1 - mx), e2 = __expf(ev2 - mx);
            float sm = e0 + e1 + e2;
            #pragma unroll
            for (int m = 16; m >= 1; m >>= 1) sm += __shfl_xor(sm, m, 32);
            float inv = 1.f / sm;
            awv[l*8 + bS]     = e0*inv;
            awv[(l+1)*8 + bS] = e1*inv;
            awv[(l+2)*8 + bS] = e2*inv;
        }
        // P3: ctx = sum_l aw[l] * eo[l,b,:] -> Actx. Same 32-lane group wrote
        // awv -> intra-wave LDS RAW ordered by lgkmcnt; no barrier needed.
        {
            int hh0 = lgS*2;
            float a0 = 0.f, a1 = 0.f;
            #pragma unroll 4
            for (int l = 0; l < LL; ++l){
                float av = awv[l*8 + bS];
                u32t p = *(const u16t*)&eo[((size_t)l*BT + bS)*HH + hh0];
                a0 += av*e52f(p & 0xffu);
                a1 += av*e52f(p >> 8);
            }
            Actx[aaddr(hh0,   bS)] = f2b(a0);
            Actx[aaddr(hh0+1, bS)] = f2b(a1);
        }
        __syncthreads();

        // P4: comb = [emb|ctx] @ combW^T + b via MFMA -> Acmb (bf16, A-layout)
        {
            bf16x8 ae0 = AeV[(0*4+quad)*16 + col],   ae1 = AeV[(1*4+quad)*16 + col];
            bf16x8 ax0 = ActxV[(0*4+quad)*16 + col], ax1 = ActxV[(1*4+quad)*16 + col];
            int h = wv*16 + col;
            float bz = combB[h];
            f32x4 a; a[0]=bz; a[1]=bz; a[2]=bz; a[3]=bz;
            a = __builtin_amdgcn_mfma_f32_16x16x32_bf16(ae0, Bc[0], a, 0,0,0);
            a = __builtin_amdgcn_mfma_f32_16x16x32_bf16(ae1, Bc[1], a, 0,0,0);
            a = __builtin_amdgcn_mfma_f32_16x16x32_bf16(ax0, Bc[2], a, 0,0,0);
            a = __builtin_amdgcn_mfma_f32_16x16x32_bf16(ax1, Bc[3], a, 0,0,0);
            if (quad < 2){
                #pragma unroll
                for (int r = 0; r < 4; ++r)
                    Acmb[aaddr(h, quad*4 + r)] = f2b(a[r]);
            }
        }
        __syncthreads();

        // P5: dec LSTM gates via MFMA (gate-permuted); in-register c update
        {
            bf16x8 ac0 = AcmbV[(0*4+quad)*16 + col], ac1 = AcmbV[(1*4+quad)*16 + col];
            bf16x8 ah0 = AhV[(0*4+quad)*16 + col],   ah1 = AhV[(1*4+quad)*16 + col];
            f32x4 g4[4];
            #pragma unroll
            for (int g = 0; g < 4; ++g){
                float bz = decB[g*64 + wv*16 + col];
                f32x4 a; a[0]=bz; a[1]=bz; a[2]=bz; a[3]=bz;
                a = __builtin_amdgcn_mfma_f32_16x16x32_bf16(ac0, Bd[g][0], a, 0,0,0);
                a = __builtin_amdgcn_mfma_f32_16x16x32_bf16(ac1, Bd[g][1], a, 0,0,0);
                a = __builtin_amdgcn_mfma_f32_16x16x32_bf16(ah0, Bd[g][2], a, 0,0,0);
                a = __builtin_amdgcn_mfma_f32_16x16x32_bf16(ah1, Bd[g][3], a, 0,0,0);
                g4[g] = a;
            }
            if (quad < 2){
                #pragma unroll
                for (int r = 0; r < 4; ++r){
                    int b = quad*4 + r;
                    float c = sigm(g4[1][r])*creg[r] + sigm(g4[0][r])*tanhx(g4[2][r]);
                    float h = sigm(g4[3][r])*tanhx(c);
                    creg[r] = c;
                    hdV[jmy*8 + b]     = h;
                    AhW[aaddr(jmy, b)] = f2b(h);
                }
            }
        }
        __syncthreads();

        // P7: pred = h @ outW^T + b; emit output (+seq_last); feed back
        if (tid < BT*CC){
            int i = tid & 7, b = tid >> 3;
            float a = outB[i];
            #pragma unroll
            for (int g = 0; g < 8; ++g){
                float w[8]; up8(oR[g], w);
                #pragma unroll
                for (int q = 0; q < 8; ++q) a += w[q]*hdV[(g*8+q)*8 + b];
            }
            predV[i*8 + b] = a;
            stf<F32>(outp, ((size_t)(b0+b)*TT + t)*CC + i, a + slp[i*10 + b]);
        }
        __syncthreads();
    }
}

// --------------------------------------------------------------- launch -----
extern "C" void kernel_launch(void* const* d_in, const int* in_sizes, int n_in,
                              void* d_out, int out_size, void* d_ws, size_t ws_size,
                              hipStream_t stream)
{
    (void)in_sizes; (void)n_in; (void)d_ws; (void)ws_size; (void)out_size;
    fused_kernel<false><<<NB, 256, 0, stream>>>(
        d_in[0],
        d_in[4],  d_in[5],  d_in[6],  d_in[7],
        d_in[8],  d_in[9],  d_in[10], d_in[11],
        d_in[12], d_in[13], d_in[14], d_in[15],
        d_in[16], d_in[17], d_in[18], d_in[19],
        d_out);
    fused_kernel<true><<<NB, 256, 0, stream>>>(
        d_in[0],
        d_in[4],  d_in[5],  d_in[6],  d_in[7],
        d_in[8],  d_in[9],  d_in[10], d_in[11],
        d_in[12], d_in[13], d_in[14], d_in[15],
        d_in[16], d_in[17], d_in[18], d_in[19],
        d_out);
}

// Round 8
// 382.225 us; speedup vs baseline: 1.6904x; 1.1151x over previous
//
#include <hip/hip_runtime.h>

#define LL 96
#define TT 24
#define HH 64
#define CC 8
#define GG 256   // 4*H
#define BT 8     // batches per block
#define NB 512   // 4096/BT

typedef unsigned short u16t;
typedef unsigned int   u32t;
typedef unsigned char  u8t;
typedef __attribute__((ext_vector_type(8))) short bf16x8;
typedef __attribute__((ext_vector_type(4))) float f32x4;

__device__ __forceinline__ float b2f(u16t u){ union{u32t i; float f;} v; v.i=((u32t)u)<<16; return v.f; }
__device__ __forceinline__ float lo2f(u32t p){ union{u32t i; float f;} v; v.i=p<<16; return v.f; }
__device__ __forceinline__ float hi2f(u32t p){ union{u32t i; float f;} v; v.i=p&0xffff0000u; return v.f; }
__device__ __forceinline__ u16t f2b(float f){ union{float f; u32t i;} v; v.f=f; u32t l=(v.i>>16)&1u; v.i+=0x7fffu+l; return (u16t)(v.i>>16); }
__device__ __forceinline__ float sigm(float x){ return 1.f/(1.f+__expf(-x)); }
// 5-inst tanh: 1 - 2/(1+e^{2x}); exact at +-inf, abs err ~1e-7 near 0 (fine at bf16 scale)
__device__ __forceinline__ float tanh2(float x){ float e=__expf(2.f*x); return 1.f - 2.f/(e+1.f); }
__device__ __forceinline__ void up8(uint4 p, float* w){
    w[0]=lo2f(p.x); w[1]=hi2f(p.x); w[2]=lo2f(p.y); w[3]=hi2f(p.y);
    w[4]=lo2f(p.z); w[5]=hi2f(p.z); w[6]=lo2f(p.w); w[7]=hi2f(p.w);
}
__device__ __forceinline__ u32t pk2(float a, float b){ return (u32t)f2b(a) | ((u32t)f2b(b)<<16); }
__device__ __forceinline__ bf16x8 u2b8(uint4 u){ union{uint4 a; bf16x8 b;} v; v.a=u; return v.b; }
// A-layout slot (k, m): [kb][quad][m=16][x=8] shorts
__device__ __forceinline__ int aaddr(int k, int m){ return (((k>>5)*4 + ((k>>3)&3))*16 + m)*8 + (k&7); }

// ---- fp8 e5m2 helpers (fallback kernel only) --------------------------------
__device__ __forceinline__ u8t f2e5(float f){
    _Float16 h = (_Float16)f;
    u16t u; __builtin_memcpy(&u, &h, 2);
    u16t r = (u16t)(u + 0xFFu + ((u >> 8) & 1u));
    return (u8t)(r >> 8);
}
__device__ __forceinline__ float e52f(u32t b){
    u16t u = (u16t)(b << 8);
    _Float16 h; __builtin_memcpy(&h, &u, 2);
    return (float)h;
}

// ---- dtype-agnostic load/store helpers --------------------------------------
template<bool F32> __device__ __forceinline__ float ldf(const void* p, size_t i){
    if constexpr (F32) return ((const float*)p)[i];
    else               return b2f(((const u16t*)p)[i]);
}
template<bool F32> __device__ __forceinline__ uint4 ld8p(const void* p, size_t i){
    if constexpr (F32){
        const float* f = (const float*)p + i;
        uint4 r; r.x = pk2(f[0],f[1]); r.y = pk2(f[2],f[3]);
                 r.z = pk2(f[4],f[5]); r.w = pk2(f[6],f[7]);
        return r;
    } else return *(const uint4*)((const u16t*)p + i);
}
template<bool F32> __device__ __forceinline__ u32t ld2p(const void* p, size_t i){
    if constexpr (F32){ const float* f = (const float*)p + i; return pk2(f[0],f[1]); }
    else return *(const u32t*)((const u16t*)p + i);
}
template<bool F32> __device__ __forceinline__ void stf(void* p, size_t i, float v){
    if constexpr (F32) ((float*)p)[i] = v;
    else               ((u16t*)p)[i] = f2b(v);
}
template<bool F32> __device__ __forceinline__ float ldW_enc(const void* wih, const void* whh, int r, int k){
    if (k < CC)      return ldf<F32>(wih, (size_t)r*CC + k);
    else if (k < 72) return ldf<F32>(whh, (size_t)r*HH + (k-CC));
    else             return 0.f;
}

// dtype probe (bf16 confirmed live by R5 FETCH_SIZE; kept as cheap insurance)
__device__ __forceinline__ bool inputs_are_f32(const void* bih){
    const u16t* p = (const u16t*)bih;
    int cnt = 0;
    #pragma unroll
    for (int i = 0; i < 64; ++i){
        u32t e = ((u32t)p[i] >> 7) & 0xFFu;
        cnt += (e >= 128u) ? 1 : 0;
    }
    return cnt > 0;
}

// =============================================================================
// Primary kernel: eo -> global bf16 in MFMA-B-fragment layout (d_ws), decoder
// P1/P3/P7 MFMA-ized. Requires ws_size >= 4096*96*64*2 bytes.
// eoG addr(b,h,t) = ((b*4+(h>>4))*3+(t>>5))*512 + ((t>>3)&3)*128 + (h&15)*8 + (t&7)
// =============================================================================
template<bool F32>
__global__ __launch_bounds__(256,2) void fused_g(
    const void* __restrict__ x_enc,
    const void* __restrict__ eWih, const void* __restrict__ eWhh,
    const void* __restrict__ ebih, const void* __restrict__ ebhh,
    const void* __restrict__ embW, const void* __restrict__ embb,
    const void* __restrict__ attnW, const void* __restrict__ attnb,
    const void* __restrict__ combW, const void* __restrict__ combb,
    const void* __restrict__ dWih, const void* __restrict__ dWhh,
    const void* __restrict__ dbih, const void* __restrict__ dbhh,
    const void* __restrict__ outW, const void* __restrict__ outb,
    void* __restrict__ outp, u16t* __restrict__ eoG)
{
    if (inputs_are_f32(ebih) != F32) return;

    __shared__ __align__(16) float slp[CC*10];
    __shared__ __align__(16) short Abuf2[2][1536];
    __shared__ __align__(16) char  uni[18880];

    const int tid = threadIdx.x;
    const int b0  = blockIdx.x * BT;
    const int col = tid & 15, quad = (tid >> 4) & 3, wv = tid >> 6;

    // ---------------- encoder: B-fragments + bias in registers ---------------
    bf16x8 Bf[4][3];
    float  biasg[4];
    #pragma unroll
    for (int g = 0; g < 4; ++g){
        int r = g*64 + wv*16 + col;
        biasg[g] = ldf<F32>(ebih, r) + ldf<F32>(ebhh, r);
        #pragma unroll
        for (int kb = 0; kb < 3; ++kb){
            bf16x8 v;
            #pragma unroll
            for (int x = 0; x < 8; ++x){
                int k = kb*32 + quad*8 + x;
                v[x] = (short)f2b(ldW_enc<F32>(eWih, eWhh, r, k));
            }
            Bf[g][kb] = v;
        }
    }
    for (int n = tid; n < 2*1536; n += 256) ((short*)Abuf2)[n] = 0;
    float sl = 0.f; size_t xbase = 0;
    if (tid < BT*CC){ int b = tid >> 3, i = tid & 7;
        xbase = (size_t)(b0+b)*(LL*CC) + i;
        sl = ldf<F32>(x_enc, xbase + (size_t)(LL-1)*CC);
        slp[i*10 + b] = sl; }
    __syncthreads();
    if (tid < BT*CC) Abuf2[0][tid] = (short)f2b(ldf<F32>(x_enc, xbase) - sl);
    float xr = (tid < BT*CC) ? ldf<F32>(x_enc, xbase + CC) : 0.f;

    const int jmy = wv*16 + col;
    const int kh  = 8 + jmy;
    const int hwbase = aaddr(kh, 0);

    u32t ebase[4] = {0,0,0,0};
    if (quad < 2){
        #pragma unroll
        for (int r = 0; r < 4; ++r){
            u32t bg = (u32t)(b0 + quad*4 + r);
            ebase[r] = (bg*4u + (u32t)(jmy>>4))*1536u + (u32t)((jmy&15)*8);
        }
    }

    float creg[4] = {0.f,0.f,0.f,0.f};
    u16t  hb16[4] = {0,0,0,0};

    for (int t = 0; t < LL; ++t){
        __syncthreads();
        const bf16x8* AbR = (const bf16x8*)Abuf2[t & 1];
        short*        AbW = Abuf2[(t + 1) & 1];
        bf16x8 a0 = AbR[(0*4 + quad)*16 + col];
        bf16x8 a1 = AbR[(1*4 + quad)*16 + col];
        bf16x8 a2 = AbR[(2*4 + quad)*16 + col];
        f32x4 acc[4];
        #pragma unroll
        for (int g = 0; g < 4; ++g){
            f32x4 a; a[0]=biasg[g]; a[1]=biasg[g]; a[2]=biasg[g]; a[3]=biasg[g];
            a = __builtin_amdgcn_mfma_f32_16x16x32_bf16(a0, Bf[g][0], a, 0,0,0);
            a = __builtin_amdgcn_mfma_f32_16x16x32_bf16(a1, Bf[g][1], a, 0,0,0);
            a = __builtin_amdgcn_mfma_f32_16x16x32_bf16(a2, Bf[g][2], a, 0,0,0);
            acc[g] = a;
        }
        int off = (t>>5)*512 + ((t>>3)&3)*128 + (t&7);
        if (quad < 2){
            #pragma unroll
            for (int r = 0; r < 4; ++r){
                int b = quad*4 + r;
                float c = sigm(acc[1][r])*creg[r] + sigm(acc[0][r])*tanh2(acc[2][r]);
                float h = sigm(acc[3][r])*tanh2(c);
                creg[r] = c; hb16[r] = f2b(h);
                eoG[ebase[r] + off] = hb16[r];             // bf16 B-frag layout
                AbW[hwbase + b*8] = (short)hb16[r];        // h(t) -> next A buffer
            }
        }
        if (tid < BT*CC && t < LL-1){
            AbW[tid] = (short)f2b(xr - sl);
            int tn = (t+2 < LL) ? t+2 : LL-1;
            xr = ldf<F32>(x_enc, xbase + (size_t)tn*CC);
        }
    }

    // ---------------- decoder weight fragments (registers) ------------------
    bf16x8 Bd[4][4];
    #pragma unroll
    for (int g = 0; g < 4; ++g){
        int r = g*64 + wv*16 + col;
        Bd[g][0] = u2b8(ld8p<F32>(dWih, (size_t)r*HH + quad*8));
        Bd[g][1] = u2b8(ld8p<F32>(dWih, (size_t)r*HH + 32 + quad*8));
        Bd[g][2] = u2b8(ld8p<F32>(dWhh, (size_t)r*HH + quad*8));
        Bd[g][3] = u2b8(ld8p<F32>(dWhh, (size_t)r*HH + 32 + quad*8));
    }
    bf16x8 Ba[2][4];
    #pragma unroll
    for (int kb = 0; kb < 4; ++kb)
        Ba[0][kb] = u2b8(ld8p<F32>(attnW, (size_t)(wv*16+col)*128 + kb*32 + quad*8));
    if (wv < 2){
        #pragma unroll
        for (int kb = 0; kb < 4; ++kb)
            Ba[1][kb] = u2b8(ld8p<F32>(attnW, (size_t)((4+wv)*16+col)*128 + kb*32 + quad*8));
    } else {
        #pragma unroll
        for (int kb = 0; kb < 4; ++kb) Ba[1][kb] = Ba[0][kb];
    }
    bf16x8 Bc[4];
    #pragma unroll
    for (int kb = 0; kb < 4; ++kb)
        Bc[kb] = u2b8(ld8p<F32>(combW, (size_t)(wv*16+col)*128 + kb*32 + quad*8));
    bf16x8 zz = {0,0,0,0,0,0,0,0};
    bf16x8 eBf = zz;                       // embW B-frag (K=32: k<8 real, rest 0)
    if (quad == 0) eBf = u2b8(ld8p<F32>(embW, (size_t)(wv*16+col)*CC));
    bf16x8 oBf0 = zz, oBf1 = zz;           // outW B-frags (N: cols<8 real)
    if (col < CC){
        oBf0 = u2b8(ld8p<F32>(outW, (size_t)col*HH + quad*8));
        oBf1 = u2b8(ld8p<F32>(outW, (size_t)col*HH + 32 + quad*8));
    }

    // ---------------- decoder LDS views + init ----------------
    float* decB  = (float*)(uni + 0);      // 256 f
    float* attnB = (float*)(uni + 1024);   // 96 f
    float* embB  = (float*)(uni + 1408);   // 64 f
    float* combB = (float*)(uni + 1664);   // 64 f
    float* outB  = (float*)(uni + 1920);   // 8 f
    float* Lg    = (float*)(uni + 1952);   // [l][8b] logits, 3072 B
    u16t*  awB   = (u16t*)(uni + 5024);    // aw bf16 [b][96], 1536 B
    u16t*  Ae    = (u16t*)(uni + 6560);    // emb A-buf, 2048 B
    u16t*  Ah0   = (u16t*)(uni + 8608);    // h A-buf ping
    u16t*  Ah1   = (u16t*)(uni + 10656);   // h A-buf pong
    u16t*  Actx  = (u16t*)(uni + 12704);   // ctx A-buf
    u16t*  Acmb  = (u16t*)(uni + 14752);   // comb A-buf
    u16t*  Apred = (u16t*)(uni + 16800);   // pred A-buf (K=32; k>=8 zero)

    if (quad < 2){
        #pragma unroll
        for (int r = 0; r < 4; ++r) Ah0[aaddr(jmy, quad*4 + r)] = hb16[r];
    }
    decB[tid] = ldf<F32>(dbih, tid) + ldf<F32>(dbhh, tid);
    if (tid < LL) attnB[tid] = ldf<F32>(attnb, tid);
    if (tid < HH) embB[tid]  = ldf<F32>(embb, tid);
    if (tid < HH) combB[tid] = ldf<F32>(combb, tid);
    if (tid < CC) outB[tid]  = ldf<F32>(outb, tid);
    for (int n = tid; n < 1024; n += 256) Apred[n] = 0;   // pred(0)=0 + zero K-pad
    __syncthreads();                       // also drains eoG stores (vmcnt before barrier)

    // eoG fragments for this wave's 2 batches -> registers (96 VGPR)
    const u16t* ebp = eoG + (size_t)(b0 + wv*2) * 6144;
    uint4 eF0[12], eF1[12];
    #pragma unroll
    for (int f = 0; f < 12; ++f) eF0[f] = *(const uint4*)(ebp + f*512 + quad*128 + col*8);
    #pragma unroll
    for (int f = 0; f < 12; ++f) eF1[f] = *(const uint4*)(ebp + 6144 + f*512 + quad*128 + col*8);

    const int lgS = tid & 31, bS = tid >> 5;
    const bf16x8* AeV   = (const bf16x8*)Ae;
    const bf16x8* ActxV = (const bf16x8*)Actx;
    const bf16x8* AcmbV = (const bf16x8*)Acmb;
    const bf16x8* ApV   = (const bf16x8*)Apred;

    for (int t = 0; t < TT; ++t){
        u16t* AhR = (t & 1) ? Ah1 : Ah0;
        u16t* AhW = (t & 1) ? Ah0 : Ah1;
        const bf16x8* AhV = (const bf16x8*)AhR;

        // P1: emb = relu(pred @ embW^T + b) via 1 MFMA/wave -> Ae
        {
            bf16x8 ap = ApV[quad*16 + col];
            float eb = embB[wv*16 + col];
            f32x4 a; a[0]=eb; a[1]=eb; a[2]=eb; a[3]=eb;
            a = __builtin_amdgcn_mfma_f32_16x16x32_bf16(ap, eBf, a, 0,0,0);
            if (quad < 2){
                #pragma unroll
                for (int r = 0; r < 4; ++r)
                    Ae[aaddr(wv*16+col, quad*4 + r)] = f2b(fmaxf(a[r], 0.f));
            }
        }
        __syncthreads();

        // P2a: attention logits via MFMA -> Lg
        {
            bf16x8 ae0 = AeV[(0*4+quad)*16 + col], ae1 = AeV[(1*4+quad)*16 + col];
            bf16x8 ah0 = AhV[(0*4+quad)*16 + col], ah1 = AhV[(1*4+quad)*16 + col];
            const int ns = (wv < 2) ? 2 : 1;
            for (int s = 0; s < ns; ++s){
                int lt = (s == 0) ? wv : 4+wv;
                float bz = attnB[lt*16 + col];
                f32x4 a; a[0]=bz; a[1]=bz; a[2]=bz; a[3]=bz;
                a = __builtin_amdgcn_mfma_f32_16x16x32_bf16(ae0, Ba[s][0], a, 0,0,0);
                a = __builtin_amdgcn_mfma_f32_16x16x32_bf16(ae1, Ba[s][1], a, 0,0,0);
                a = __builtin_amdgcn_mfma_f32_16x16x32_bf16(ah0, Ba[s][2], a, 0,0,0);
                a = __builtin_amdgcn_mfma_f32_16x16x32_bf16(ah1, Ba[s][3], a, 0,0,0);
                if (quad < 2)
                    *(float4*)&Lg[(lt*16+col)*8 + quad*4] = make_float4(a[0],a[1],a[2],a[3]);
            }
        }
        __syncthreads();

        // P2b: softmax per batch -> awB (bf16, A-broadcast layout)
        {
            int l = lgS*3;
            float ev0 = Lg[l*8 + bS], ev1 = Lg[(l+1)*8 + bS], ev2 = Lg[(l+2)*8 + bS];
            float mx = fmaxf(ev0, fmaxf(ev1, ev2));
            #pragma unroll
            for (int m = 16; m >= 1; m >>= 1) mx = fmaxf(mx, __shfl_xor(mx, m, 32));
            float e0 = __expf(ev0 - mx), e1 = __expf(ev1 - mx), e2 = __expf(ev2 - mx);
            float sm = e0 + e1 + e2;
            #pragma unroll
            for (int m = 16; m >= 1; m >>= 1) sm += __shfl_xor(sm, m, 32);
            float inv = 1.f / sm;
            awB[bS*96 + l]     = f2b(e0*inv);
            awB[bS*96 + l + 1] = f2b(e1*inv);
            awB[bS*96 + l + 2] = f2b(e2*inv);
        }
        // P3: ctx via MFMA (A = aw broadcast rows, B = register eo frags).
        // awB written by this wave's own half-groups -> intra-wave RAW, no barrier.
        {
            const u16t* ap0 = awB + (wv*2)*96;
            bf16x8 f0 = *(const bf16x8*)(ap0 + quad*8);
            bf16x8 f1 = *(const bf16x8*)(ap0 + 32 + quad*8);
            bf16x8 f2 = *(const bf16x8*)(ap0 + 64 + quad*8);
            #pragma unroll
            for (int nt = 0; nt < 4; ++nt){
                f32x4 a; a[0]=0.f; a[1]=0.f; a[2]=0.f; a[3]=0.f;
                a = __builtin_amdgcn_mfma_f32_16x16x32_bf16(f0, u2b8(eF0[nt*3+0]), a, 0,0,0);
                a = __builtin_amdgcn_mfma_f32_16x16x32_bf16(f1, u2b8(eF0[nt*3+1]), a, 0,0,0);
                a = __builtin_amdgcn_mfma_f32_16x16x32_bf16(f2, u2b8(eF0[nt*3+2]), a, 0,0,0);
                if (quad == 0) Actx[aaddr(nt*16+col, wv*2)] = f2b(a[0]);
            }
            const u16t* ap1 = awB + (wv*2+1)*96;
            bf16x8 g0 = *(const bf16x8*)(ap1 + quad*8);
            bf16x8 g1 = *(const bf16x8*)(ap1 + 32 + quad*8);
            bf16x8 g2 = *(const bf16x8*)(ap1 + 64 + quad*8);
            #pragma unroll
            for (int nt = 0; nt < 4; ++nt){
                f32x4 a; a[0]=0.f; a[1]=0.f; a[2]=0.f; a[3]=0.f;
                a = __builtin_amdgcn_mfma_f32_16x16x32_bf16(g0, u2b8(eF1[nt*3+0]), a, 0,0,0);
                a = __builtin_amdgcn_mfma_f32_16x16x32_bf16(g1, u2b8(eF1[nt*3+1]), a, 0,0,0);
                a = __builtin_amdgcn_mfma_f32_16x16x32_bf16(g2, u2b8(eF1[nt*3+2]), a, 0,0,0);
                if (quad == 0) Actx[aaddr(nt*16+col, wv*2+1)] = f2b(a[0]);
            }
        }
        __syncthreads();

        // P4: comb = [emb|ctx] @ combW^T + b via MFMA -> Acmb
        {
            bf16x8 ae0 = AeV[(0*4+quad)*16 + col],   ae1 = AeV[(1*4+quad)*16 + col];
            bf16x8 ax0 = ActxV[(0*4+quad)*16 + col], ax1 = ActxV[(1*4+quad)*16 + col];
            float bz = combB[wv*16 + col];
            f32x4 a; a[0]=bz; a[1]=bz; a[2]=bz; a[3]=bz;
            a = __builtin_amdgcn_mfma_f32_16x16x32_bf16(ae0, Bc[0], a, 0,0,0);
            a = __builtin_amdgcn_mfma_f32_16x16x32_bf16(ae1, Bc[1], a, 0,0,0);
            a = __builtin_amdgcn_mfma_f32_16x16x32_bf16(ax0, Bc[2], a, 0,0,0);
            a = __builtin_amdgcn_mfma_f32_16x16x32_bf16(ax1, Bc[3], a, 0,0,0);
            if (quad < 2){
                #pragma unroll
                for (int r = 0; r < 4; ++r)
                    Acmb[aaddr(wv*16+col, quad*4 + r)] = f2b(a[r]);
            }
        }
        __syncthreads();

        // P5: dec LSTM gates via MFMA; in-register c update; h -> AhW
        {
            bf16x8 ac0 = AcmbV[(0*4+quad)*16 + col], ac1 = AcmbV[(1*4+quad)*16 + col];
            bf16x8 ah0 = AhV[(0*4+quad)*16 + col],   ah1 = AhV[(1*4+quad)*16 + col];
            f32x4 g4[4];
            #pragma unroll
            for (int g = 0; g < 4; ++g){
                float bz = decB[g*64 + wv*16 + col];
                f32x4 a; a[0]=bz; a[1]=bz; a[2]=bz; a[3]=bz;
                a = __builtin_amdgcn_mfma_f32_16x16x32_bf16(ac0, Bd[g][0], a, 0,0,0);
                a = __builtin_amdgcn_mfma_f32_16x16x32_bf16(ac1, Bd[g][1], a, 0,0,0);
                a = __builtin_amdgcn_mfma_f32_16x16x32_bf16(ah0, Bd[g][2], a, 0,0,0);
                a = __builtin_amdgcn_mfma_f32_16x16x32_bf16(ah1, Bd[g][3], a, 0,0,0);
                g4[g] = a;
            }
            if (quad < 2){
                #pragma unroll
                for (int r = 0; r < 4; ++r){
                    int b = quad*4 + r;
                    float c = sigm(g4[1][r])*creg[r] + sigm(g4[0][r])*tanh2(g4[2][r]);
                    float h = sigm(g4[3][r])*tanh2(c);
                    creg[r] = c;
                    AhW[aaddr(jmy, b)] = f2b(h);
                }
            }
        }
        __syncthreads();

        // P7: pred = h @ outW^T + b via 2 MFMA on wave 0; -> Apred + outp
        if (wv == 0){
            const bf16x8* AhWV = (const bf16x8*)AhW;
            bf16x8 xh0 = AhWV[(0*4+quad)*16 + col];
            bf16x8 xh1 = AhWV[(1*4+quad)*16 + col];
            float ob = outB[col & 7];
            f32x4 a; a[0]=ob; a[1]=ob; a[2]=ob; a[3]=ob;
            a = __builtin_amdgcn_mfma_f32_16x16x32_bf16(xh0, oBf0, a, 0,0,0);
            a = __builtin_amdgcn_mfma_f32_16x16x32_bf16(xh1, oBf1, a, 0,0,0);
            if (quad < 2 && col < CC){
                #pragma unroll
                for (int r = 0; r < 4; ++r){
                    int b = quad*4 + r;
                    float p = a[r];
                    Apred[aaddr(col, b)] = f2b(p);
                    stf<F32>(outp, ((size_t)(b0+b)*TT + t)*CC + col, p + slp[col*10 + b]);
                }
            }
        }
        __syncthreads();
    }
}

// =============================================================================
// Fallback (R7, proven 356 us): eo as fp8 e5m2 in LDS; scalar P1/P3/P7.
// =============================================================================
template<bool F32>
__global__ __launch_bounds__(256,2) void fused_fb(
    const void* __restrict__ x_enc,
    const void* __restrict__ eWih, const void* __restrict__ eWhh,
    const void* __restrict__ ebih, const void* __restrict__ ebhh,
    const void* __restrict__ embW, const void* __restrict__ embb,
    const void* __restrict__ attnW, const void* __restrict__ attnb,
    const void* __restrict__ combW, const void* __restrict__ combb,
    const void* __restrict__ dWih, const void* __restrict__ dWhh,
    const void* __restrict__ dbih, const void* __restrict__ dbhh,
    const void* __restrict__ outW, const void* __restrict__ outb,
    void* __restrict__ outp)
{
    if (inputs_are_f32(ebih) != F32) return;

    __shared__ __align__(16) u8t   eo[LL*BT*HH];
    __shared__ __align__(16) float slp[CC*10];
    __shared__ __align__(16) short Abuf2[2][1536];
    __shared__ __align__(16) char  uni[20640];

    const int tid = threadIdx.x;
    const int b0  = blockIdx.x * BT;
    const int col = tid & 15, quad = (tid >> 4) & 3, wv = tid >> 6;

    bf16x8 Bf[4][3];
    float  biasg[4];
    #pragma unroll
    for (int g = 0; g < 4; ++g){
        int r = g*64 + wv*16 + col;
        biasg[g] = ldf<F32>(ebih, r) + ldf<F32>(ebhh, r);
        #pragma unroll
        for (int kb = 0; kb < 3; ++kb){
            bf16x8 v;
            #pragma unroll
            for (int x = 0; x < 8; ++x){
                int k = kb*32 + quad*8 + x;
                v[x] = (short)f2b(ldW_enc<F32>(eWih, eWhh, r, k));
            }
            Bf[g][kb] = v;
        }
    }
    for (int n = tid; n < 2*1536; n += 256) ((short*)Abuf2)[n] = 0;
    float sl = 0.f; size_t xbase = 0;
    if (tid < BT*CC){ int b = tid >> 3, i = tid & 7;
        xbase = (size_t)(b0+b)*(LL*CC) + i;
        sl = ldf<F32>(x_enc, xbase + (size_t)(LL-1)*CC);
        slp[i*10 + b] = sl; }
    __syncthreads();
    if (tid < BT*CC) Abuf2[0][tid] = (short)f2b(ldf<F32>(x_enc, xbase) - sl);
    float xr = (tid < BT*CC) ? ldf<F32>(x_enc, xbase + CC) : 0.f;

    const int jmy = wv*16 + col;
    const int kh  = 8 + jmy;
    const int hwbase = aaddr(kh, 0);

    float creg[4] = {0.f,0.f,0.f,0.f};
    float hfin[4] = {0.f,0.f,0.f,0.f};
    u16t  hb16[4] = {0,0,0,0};

    for (int t = 0; t < LL; ++t){
        __syncthreads();
        const bf16x8* AbR = (const bf16x8*)Abuf2[t & 1];
        short*        AbW = Abuf2[(t + 1) & 1];
        bf16x8 a0 = AbR[(0*4 + quad)*16 + col];
        bf16x8 a1 = AbR[(1*4 + quad)*16 + col];
        bf16x8 a2 = AbR[(2*4 + quad)*16 + col];
        f32x4 acc[4];
        #pragma unroll
        for (int g = 0; g < 4; ++g){
            f32x4 a; a[0]=biasg[g]; a[1]=biasg[g]; a[2]=biasg[g]; a[3]=biasg[g];
            a = __builtin_amdgcn_mfma_f32_16x16x32_bf16(a0, Bf[g][0], a, 0,0,0);
            a = __builtin_amdgcn_mfma_f32_16x16x32_bf16(a1, Bf[g][1], a, 0,0,0);
            a = __builtin_amdgcn_mfma_f32_16x16x32_bf16(a2, Bf[g][2], a, 0,0,0);
            acc[g] = a;
        }
        if (quad < 2){
            #pragma unroll
            for (int r = 0; r < 4; ++r){
                int b = quad*4 + r;
                float c = sigm(acc[1][r])*creg[r] + sigm(acc[0][r])*tanh2(acc[2][r]);
                float h = sigm(acc[3][r])*tanh2(c);
                creg[r] = c; hfin[r] = h; hb16[r] = f2b(h);
                eo[((size_t)t*BT + b)*HH + jmy] = f2e5(h);
                AbW[hwbase + b*8] = (short)hb16[r];
            }
        }
        if (tid < BT*CC && t < LL-1){
            AbW[tid] = (short)f2b(xr - sl);
            int tn = (t+2 < LL) ? t+2 : LL-1;
            xr = ldf<F32>(x_enc, xbase + (size_t)tn*CC);
        }
    }

    bf16x8 Bd[4][4];
    #pragma unroll
    for (int g = 0; g < 4; ++g){
        int r = g*64 + wv*16 + col;
        Bd[g][0] = u2b8(ld8p<F32>(dWih, (size_t)r*HH + quad*8));
        Bd[g][1] = u2b8(ld8p<F32>(dWih, (size_t)r*HH + 32 + quad*8));
        Bd[g][2] = u2b8(ld8p<F32>(dWhh, (size_t)r*HH + quad*8));
        Bd[g][3] = u2b8(ld8p<F32>(dWhh, (size_t)r*HH + 32 + quad*8));
    }
    bf16x8 Ba[2][4];
    #pragma unroll
    for (int kb = 0; kb < 4; ++kb)
        Ba[0][kb] = u2b8(ld8p<F32>(attnW, (size_t)(wv*16+col)*128 + kb*32 + quad*8));
    if (wv < 2){
        #pragma unroll
        for (int kb = 0; kb < 4; ++kb)
            Ba[1][kb] = u2b8(ld8p<F32>(attnW, (size_t)((4+wv)*16+col)*128 + kb*32 + quad*8));
    } else {
        #pragma unroll
        for (int kb = 0; kb < 4; ++kb) Ba[1][kb] = Ba[0][kb];
    }
    bf16x8 Bc[4];
    #pragma unroll
    for (int kb = 0; kb < 4; ++kb)
        Bc[kb] = u2b8(ld8p<F32>(combW, (size_t)(wv*16+col)*128 + kb*32 + quad*8));
    u32t eR[4];
    { int h = tid & 63;
      #pragma unroll
      for (int g = 0; g < 4; ++g) eR[g] = ld2p<F32>(embW, (size_t)h*CC + g*2); }
    uint4 oR[8];
    if (tid < BT*CC){ int i = tid & 7;
        #pragma unroll
        for (int g = 0; g < 8; ++g) oR[g] = ld8p<F32>(outW, (size_t)i*HH + g*8); }

    float* decB  = (float*)(uni + 0);
    float* attnB = (float*)(uni + 1024);
    float* embB  = (float*)(uni + 1408);
    float* combB = (float*)(uni + 1664);
    float* outB  = (float*)(uni + 1920);
    float* awv   = (float*)(uni + 1952);
    float* Lg    = (float*)(uni + 5024);
    float* hdV   = (float*)(uni + 8096);
    float* predV = (float*)(uni + 10144);
    u16t*  Ae    = (u16t*)(uni + 10400);
    u16t*  Ah0   = (u16t*)(uni + 12448);
    u16t*  Ah1   = (u16t*)(uni + 14496);
    u16t*  Actx  = (u16t*)(uni + 16544);
    u16t*  Acmb  = (u16t*)(uni + 18592);

    if (quad < 2){
        #pragma unroll
        for (int r = 0; r < 4; ++r){
            int b = quad*4 + r;
            hdV[jmy*8 + b]      = hfin[r];
            Ah0[aaddr(jmy, b)]  = hb16[r];
        }
    }
    decB[tid] = ldf<F32>(dbih, tid) + ldf<F32>(dbhh, tid);
    if (tid < LL) attnB[tid] = ldf<F32>(attnb, tid);
    if (tid < HH) embB[tid]  = ldf<F32>(embb, tid);
    if (tid < HH) combB[tid] = ldf<F32>(combb, tid);
    if (tid < CC) outB[tid]  = ldf<F32>(outb, tid);
    if (tid < 64) predV[tid] = 0.f;
    __syncthreads();

    const int hA  = tid & 63, bqA = tid >> 6;
    const int bS  = tid >> 5, lgS = tid & 31;
    const bf16x8* AeV   = (const bf16x8*)Ae;
    const bf16x8* ActxV = (const bf16x8*)Actx;
    const bf16x8* AcmbV = (const bf16x8*)Acmb;

    for (int t = 0; t < TT; ++t){
        u16t* AhR = (t & 1) ? Ah1 : Ah0;
        u16t* AhW = (t & 1) ? Ah0 : Ah1;
        const bf16x8* AhV = (const bf16x8*)AhR;

        {
            int ba = bqA*2;
            float a0 = embB[hA], a1 = a0;
            #pragma unroll
            for (int g = 0; g < 4; ++g){
                u32t p = eR[g];
                float w0 = lo2f(p), w1 = hi2f(p);
                float2 pv0 = *(const float2*)&predV[(g*2)*8 + ba];
                float2 pv1 = *(const float2*)&predV[(g*2+1)*8 + ba];
                a0 += w0*pv0.x + w1*pv1.x;
                a1 += w0*pv0.y + w1*pv1.y;
            }
            Ae[aaddr(hA, ba)]   = f2b(fmaxf(a0, 0.f));
            Ae[aaddr(hA, ba+1)] = f2b(fmaxf(a1, 0.f));
        }
        __syncthreads();

        {
            bf16x8 ae0 = AeV[(0*4+quad)*16 + col], ae1 = AeV[(1*4+quad)*16 + col];
            bf16x8 ah0 = AhV[(0*4+quad)*16 + col], ah1 = AhV[(1*4+quad)*16 + col];
            const int ns = (wv < 2) ? 2 : 1;
            for (int s = 0; s < ns; ++s){
                int lt = (s == 0) ? wv : 4+wv;
                float bz = attnB[lt*16 + col];
                f32x4 a; a[0]=bz; a[1]=bz; a[2]=bz; a[3]=bz;
                a = __builtin_amdgcn_mfma_f32_16x16x32_bf16(ae0, Ba[s][0], a, 0,0,0);
                a = __builtin_amdgcn_mfma_f32_16x16x32_bf16(ae1, Ba[s][1], a, 0,0,0);
                a = __builtin_amdgcn_mfma_f32_16x16x32_bf16(ah0, Ba[s][2], a, 0,0,0);
                a = __builtin_amdgcn_mfma_f32_16x16x32_bf16(ah1, Ba[s][3], a, 0,0,0);
                if (quad < 2)
                    *(float4*)&Lg[(lt*16+col)*8 + quad*4] = make_float4(a[0],a[1],a[2],a[3]);
            }
        }
        __syncthreads();

        {
            int l = lgS*3;
            float ev0 = Lg[l*8 + bS], ev1 = Lg[(l+1)*8 + bS], ev2 = Lg[(l+2)*8 + bS];
            float mx = fmaxf(ev0, fmaxf(ev1, ev2));
            #pragma unroll
            for (int m = 16; m >= 1; m >>= 1) mx = fmaxf(mx, __shfl_xor(mx, m, 32));
            float e0 = __expf(ev0 - mx), e1 = __expf(ev1 - mx), e2 = __expf(ev2 - mx);
            float sm = e0 + e1 + e2;
            #pragma unroll
            for (int m = 16; m >= 1; m >>= 1) sm += __shfl_xor(sm, m, 32);
            float inv = 1.f / sm;
            awv[l*8 + bS]     = e0*inv;
            awv[(l+1)*8 + bS] = e1*inv;
            awv[(l+2)*8 + bS] = e2*inv;
        }
        {
            int hh0 = lgS*2;
            float a0 = 0.f, a1 = 0.f;
            #pragma unroll 4
            for (int l = 0; l < LL; ++l){
                float av = awv[l*8 + bS];
                u32t p = *(const u16t*)&eo[((size_t)l*BT + bS)*HH + hh0];
                a0 += av*e52f(p & 0xffu);
                a1 += av*e52f(p >> 8);
            }
            Actx[aaddr(hh0,   bS)] = f2b(a0);
            Actx[aaddr(hh0+1, bS)] = f2b(a1);
        }
        __syncthreads();

        {
            bf16x8 ae0 = AeV[(0*4+quad)*16 + col],   ae1 = AeV[(1*4+quad)*16 + col];
            bf16x8 ax0 = ActxV[(0*4+quad)*16 + col], ax1 = ActxV[(1*4+quad)*16 + col];
            int h = wv*16 + col;
            float bz = combB[h];
            f32x4 a; a[0]=bz; a[1]=bz; a[2]=bz; a[3]=bz;
            a = __builtin_amdgcn_mfma_f32_16x16x32_bf16(ae0, Bc[0], a, 0,0,0);
            a = __builtin_amdgcn_mfma_f32_16x16x32_bf16(ae1, Bc[1], a, 0,0,0);
            a = __builtin_amdgcn_mfma_f32_16x16x32_bf16(ax0, Bc[2], a, 0,0,0);
            a = __builtin_amdgcn_mfma_f32_16x16x32_bf16(ax1, Bc[3], a, 0,0,0);
            if (quad < 2){
                #pragma unroll
                for (int r = 0; r < 4; ++r)
                    Acmb[aaddr(h, quad*4 + r)] = f2b(a[r]);
            }
        }
        __syncthreads();

        {
            bf16x8 ac0 = AcmbV[(0*4+quad)*16 + col], ac1 = AcmbV[(1*4+quad)*16 + col];
            bf16x8 ah0 = AhV[(0*4+quad)*16 + col],   ah1 = AhV[(1*4+quad)*16 + col];
            f32x4 g4[4];
            #pragma unroll
            for (int g = 0; g < 4; ++g){
                float bz = decB[g*64 + wv*16 + col];
                f32x4 a; a[0]=bz; a[1]=bz; a[2]=bz; a[3]=bz;
                a = __builtin_amdgcn_mfma_f32_16x16x32_bf16(ac0, Bd[g][0], a, 0,0,0);
                a = __builtin_amdgcn_mfma_f32_16x16x32_bf16(ac1, Bd[g][1], a, 0,0,0);
                a = __builtin_amdgcn_mfma_f32_16x16x32_bf16(ah0, Bd[g][2], a, 0,0,0);
                a = __builtin_amdgcn_mfma_f32_16x16x32_bf16(ah1, Bd[g][3], a, 0,0,0);
                g4[g] = a;
            }
            if (quad < 2){
                #pragma unroll
                for (int r = 0; r < 4; ++r){
                    int b = quad*4 + r;
                    float c = sigm(g4[1][r])*creg[r] + sigm(g4[0][r])*tanh2(g4[2][r]);
                    float h = sigm(g4[3][r])*tanh2(c);
                    creg[r] = c;
                    hdV[jmy*8 + b]     = h;
                    AhW[aaddr(jmy, b)] = f2b(h);
                }
            }
        }
        __syncthreads();

        if (tid < BT*CC){
            int i = tid & 7, b = tid >> 3;
            float a = outB[i];
            #pragma unroll
            for (int g = 0; g < 8; ++g){
                float w[8]; up8(oR[g], w);
                #pragma unroll
                for (int q = 0; q < 8; ++q) a += w[q]*hdV[(g*8+q)*8 + b];
            }
            predV[i*8 + b] = a;
            stf<F32>(outp, ((size_t)(b0+b)*TT + t)*CC + i, a + slp[i*10 + b]);
        }
        __syncthreads();
    }
}

// --------------------------------------------------------------- launch -----
extern "C" void kernel_launch(void* const* d_in, const int* in_sizes, int n_in,
                              void* d_out, int out_size, void* d_ws, size_t ws_size,
                              hipStream_t stream)
{
    (void)in_sizes; (void)n_in; (void)out_size;
    const size_t need = (size_t)4096 * LL * HH * sizeof(u16t);   // 50331648
    if (ws_size >= need){
        fused_g<false><<<NB, 256, 0, stream>>>(
            d_in[0],
            d_in[4],  d_in[5],  d_in[6],  d_in[7],
            d_in[8],  d_in[9],  d_in[10], d_in[11],
            d_in[12], d_in[13], d_in[14], d_in[15],
            d_in[16], d_in[17], d_in[18], d_in[19],
            d_out, (u16t*)d_ws);
        fused_g<true><<<NB, 256, 0, stream>>>(
            d_in[0],
            d_in[4],  d_in[5],  d_in[6],  d_in[7],
            d_in[8],  d_in[9],  d_in[10], d_in[11],
            d_in[12], d_in[13], d_in[14], d_in[15],
            d_in[16], d_in[17], d_in[18], d_in[19],
            d_out, (u16t*)d_ws);
    } else {
        fused_fb<false><<<NB, 256, 0, stream>>>(
            d_in[0],
            d_in[4],  d_in[5],  d_in[6],  d_in[7],
            d_in[8],  d_in[9],  d_in[10], d_in[11],
            d_in[12], d_in[13], d_in[14], d_in[15],
            d_in[16], d_in[17], d_in[18], d_in[19],
            d_out);
        fused_fb<true><<<NB, 256, 0, stream>>>(
            d_in[0],
            d_in[4],  d_in[5],  d_in[6],  d_in[7],
            d_in[8],  d_in[9],  d_in[10], d_in[11],
            d_in[12], d_in[13], d_in[14], d_in[15],
            d_in[16], d_in[17], d_in[18], d_in[19],
            d_out);
    }
}

// Round 9
// 292.565 us; speedup vs baseline: 2.2085x; 1.3065x over previous
//
#include <hip/hip_runtime.h>

#define LL 96
#define TT 24
#define HH 64
#define CC 8
#define GG 256   // 4*H
#define BT 8     // batches per block
#define NB 512   // 4096/BT

typedef unsigned short u16t;
typedef unsigned int   u32t;
typedef __attribute__((ext_vector_type(8))) short bf16x8;
typedef __attribute__((ext_vector_type(4))) float f32x4;

__device__ __forceinline__ float b2f(u16t u){ union{u32t i; float f;} v; v.i=((u32t)u)<<16; return v.f; }
__device__ __forceinline__ float lo2f(u32t p){ union{u32t i; float f;} v; v.i=p<<16; return v.f; }
__device__ __forceinline__ float hi2f(u32t p){ union{u32t i; float f;} v; v.i=p&0xffff0000u; return v.f; }
__device__ __forceinline__ u16t f2b(float f){ union{float f; u32t i;} v; v.f=f; u32t l=(v.i>>16)&1u; v.i+=0x7fffu+l; return (u16t)(v.i>>16); }
__device__ __forceinline__ float rcpf(float x){ return __builtin_amdgcn_rcpf(x); }
// fast sigmoid/tanh: v_exp + v_rcp (1-ulp), no precise-div chains
__device__ __forceinline__ float sigm(float x){ return rcpf(1.f + __expf(-x)); }
__device__ __forceinline__ float tanh2(float x){ return 1.f - 2.f*rcpf(__expf(2.f*x) + 1.f); }
__device__ __forceinline__ u32t pk2(float a, float b){ return (u32t)f2b(a) | ((u32t)f2b(b)<<16); }
__device__ __forceinline__ bf16x8 u2b8(uint4 u){ union{uint4 a; bf16x8 b;} v; v.a=u; return v.b; }
// A-layout slot (k, m): [kb][quad][m=16][x=8] shorts
__device__ __forceinline__ int aaddr(int k, int m){ return (((k>>5)*4 + ((k>>3)&3))*16 + m)*8 + (k&7); }

// ---- dtype-agnostic load/store helpers --------------------------------------
template<bool F32> __device__ __forceinline__ float ldf(const void* p, size_t i){
    if constexpr (F32) return ((const float*)p)[i];
    else               return b2f(((const u16t*)p)[i]);
}
template<bool F32> __device__ __forceinline__ uint4 ld8p(const void* p, size_t i){
    if constexpr (F32){
        const float* f = (const float*)p + i;
        uint4 r; r.x = pk2(f[0],f[1]); r.y = pk2(f[2],f[3]);
                 r.z = pk2(f[4],f[5]); r.w = pk2(f[6],f[7]);
        return r;
    } else return *(const uint4*)((const u16t*)p + i);
}
template<bool F32> __device__ __forceinline__ void stf(void* p, size_t i, float v){
    if constexpr (F32) ((float*)p)[i] = v;
    else               ((u16t*)p)[i] = f2b(v);
}
template<bool F32> __device__ __forceinline__ float ldW_enc(const void* wih, const void* whh, int r, int k){
    if (k < CC)      return ldf<F32>(wih, (size_t)r*CC + k);
    else if (k < 72) return ldf<F32>(whh, (size_t)r*HH + (k-CC));
    else             return 0.f;
}

// dtype probe (bf16 confirmed live; kept as cheap insurance)
__device__ __forceinline__ bool inputs_are_f32(const void* bih){
    const u16t* p = (const u16t*)bih;
    int cnt = 0;
    #pragma unroll
    for (int i = 0; i < 64; ++i){
        u32t e = ((u32t)p[i] >> 7) & 0xFFu;
        cnt += (e >= 128u) ? 1 : 0;
    }
    return cnt > 0;
}

// =============================================================================
// Fused MFMA encoder+decoder. A-buffers carry batches duplicated in M-rows
// 8-15 so MFMA C rows 8-15 are valid duplicates -> nonlinear updates spread
// over all 4 quads at 2 elems/lane (mapping: quads{0,1} use r{0,1}, quads
// {2,3} use r{2,3}; batch b=(quad*4+r)&7). eo lives in d_ws (bf16, B-frag
// layout): addr(b,h,t) = ((b*4+(h>>4))*3+(t>>5))*512+((t>>3)&3)*128+(h&15)*8+(t&7)
// =============================================================================
template<bool F32>
__global__ __launch_bounds__(256,2) void fused_g(
    const void* __restrict__ x_enc,
    const void* __restrict__ eWih, const void* __restrict__ eWhh,
    const void* __restrict__ ebih, const void* __restrict__ ebhh,
    const void* __restrict__ embW, const void* __restrict__ embb,
    const void* __restrict__ attnW, const void* __restrict__ attnb,
    const void* __restrict__ combW, const void* __restrict__ combb,
    const void* __restrict__ dWih, const void* __restrict__ dWhh,
    const void* __restrict__ dbih, const void* __restrict__ dbhh,
    const void* __restrict__ outW, const void* __restrict__ outb,
    void* __restrict__ outp, u16t* __restrict__ eoG)
{
    if (inputs_are_f32(ebih) != F32) return;

    __shared__ __align__(16) float slp[CC*10];
    __shared__ __align__(16) short Abuf2[2][1536];
    __shared__ __align__(16) char  uni[18880];

    const int tid = threadIdx.x;
    const int b0  = blockIdx.x * BT;
    const int col = tid & 15, quad = (tid >> 4) & 3, wv = tid >> 6;
    const int r0  = (quad >> 1) * 2;              // this lane's C rows r0,r0+1

    // ---------------- encoder: B-fragments + bias in registers ---------------
    bf16x8 Bf[4][3];
    float  biasg[4];
    #pragma unroll
    for (int g = 0; g < 4; ++g){
        int r = g*64 + wv*16 + col;
        biasg[g] = ldf<F32>(ebih, r) + ldf<F32>(ebhh, r);
        #pragma unroll
        for (int kb = 0; kb < 3; ++kb){
            bf16x8 v;
            #pragma unroll
            for (int x = 0; x < 8; ++x){
                int k = kb*32 + quad*8 + x;
                v[x] = (short)f2b(ldW_enc<F32>(eWih, eWhh, r, k));
            }
            Bf[g][kb] = v;
        }
    }
    for (int n = tid; n < 2*1536; n += 256) ((short*)Abuf2)[n] = 0;
    float sl = 0.f; size_t xbase = 0;
    if (tid < BT*CC){ int b = tid >> 3, i = tid & 7;
        xbase = (size_t)(b0+b)*(LL*CC) + i;
        sl = ldf<F32>(x_enc, xbase + (size_t)(LL-1)*CC);
        slp[i*10 + b] = sl; }
    __syncthreads();
    if (tid < BT*CC){ short v = (short)f2b(ldf<F32>(x_enc, xbase) - sl);
        Abuf2[0][tid] = v; Abuf2[0][tid + 64] = v; }          // x(0) + dup rows
    float xr = (tid < BT*CC) ? ldf<F32>(x_enc, xbase + CC) : 0.f;

    const int jmy = wv*16 + col;
    const int kh  = 8 + jmy;
    const int hwbase = aaddr(kh, 0);

    u32t ebase[2];
    #pragma unroll
    for (int rr = 0; rr < 2; ++rr){
        u32t bg = (u32t)(b0 + ((quad*4 + r0 + rr) & 7));
        ebase[rr] = (bg*4u + (u32t)(jmy>>4))*1536u + (u32t)((jmy&15)*8);
    }

    float creg[2] = {0.f,0.f};
    u16t  hb16[2] = {0,0};

    for (int t = 0; t < LL; ++t){
        __syncthreads();
        const bf16x8* AbR = (const bf16x8*)Abuf2[t & 1];
        short*        AbW = Abuf2[(t + 1) & 1];
        bf16x8 a0 = AbR[(0*4 + quad)*16 + col];
        bf16x8 a1 = AbR[(1*4 + quad)*16 + col];
        bf16x8 a2 = AbR[(2*4 + quad)*16 + col];
        f32x4 acc[4];
        #pragma unroll
        for (int g = 0; g < 4; ++g){
            f32x4 a; a[0]=biasg[g]; a[1]=biasg[g]; a[2]=biasg[g]; a[3]=biasg[g];
            a = __builtin_amdgcn_mfma_f32_16x16x32_bf16(a0, Bf[g][0], a, 0,0,0);
            a = __builtin_amdgcn_mfma_f32_16x16x32_bf16(a1, Bf[g][1], a, 0,0,0);
            a = __builtin_amdgcn_mfma_f32_16x16x32_bf16(a2, Bf[g][2], a, 0,0,0);
            acc[g] = a;
        }
        int off = (t>>5)*512 + ((t>>3)&3)*128 + (t&7);
        // update on ALL lanes, 2 elems each
        #pragma unroll
        for (int rr = 0; rr < 2; ++rr){
            int r = r0 + rr;
            int b = (quad*4 + r) & 7;
            float c = sigm(acc[1][r])*creg[rr] + sigm(acc[0][r])*tanh2(acc[2][r]);
            float h = sigm(acc[3][r])*tanh2(c);
            creg[rr] = c; hb16[rr] = f2b(h);
            eoG[ebase[rr] + off] = hb16[rr];
            AbW[hwbase + b*8]     = (short)hb16[rr];
            AbW[hwbase + (b+8)*8] = (short)hb16[rr];
        }
        if (tid < BT*CC && t < LL-1){
            short v = (short)f2b(xr - sl);
            AbW[tid] = v; AbW[tid + 64] = v;
            int tn = (t+2 < LL) ? t+2 : LL-1;
            xr = ldf<F32>(x_enc, xbase + (size_t)tn*CC);
        }
    }

    // ---------------- decoder weight fragments (registers) ------------------
    bf16x8 Bd[4][4];
    #pragma unroll
    for (int g = 0; g < 4; ++g){
        int r = g*64 + wv*16 + col;
        Bd[g][0] = u2b8(ld8p<F32>(dWih, (size_t)r*HH + quad*8));
        Bd[g][1] = u2b8(ld8p<F32>(dWih, (size_t)r*HH + 32 + quad*8));
        Bd[g][2] = u2b8(ld8p<F32>(dWhh, (size_t)r*HH + quad*8));
        Bd[g][3] = u2b8(ld8p<F32>(dWhh, (size_t)r*HH + 32 + quad*8));
    }
    bf16x8 Ba[2][4];
    #pragma unroll
    for (int kb = 0; kb < 4; ++kb)
        Ba[0][kb] = u2b8(ld8p<F32>(attnW, (size_t)(wv*16+col)*128 + kb*32 + quad*8));
    if (wv < 2){
        #pragma unroll
        for (int kb = 0; kb < 4; ++kb)
            Ba[1][kb] = u2b8(ld8p<F32>(attnW, (size_t)((4+wv)*16+col)*128 + kb*32 + quad*8));
    } else {
        #pragma unroll
        for (int kb = 0; kb < 4; ++kb) Ba[1][kb] = Ba[0][kb];
    }
    bf16x8 Bc[4];
    #pragma unroll
    for (int kb = 0; kb < 4; ++kb)
        Bc[kb] = u2b8(ld8p<F32>(combW, (size_t)(wv*16+col)*128 + kb*32 + quad*8));
    bf16x8 zz = {0,0,0,0,0,0,0,0};
    bf16x8 eBf = zz;                       // embW B-frag (K=32: k<8 real)
    if (quad == 0) eBf = u2b8(ld8p<F32>(embW, (size_t)(wv*16+col)*CC));
    bf16x8 oBf0 = zz, oBf1 = zz;           // outW B-frags (n=col<8 real)
    if (col < CC){
        oBf0 = u2b8(ld8p<F32>(outW, (size_t)col*HH + quad*8));
        oBf1 = u2b8(ld8p<F32>(outW, (size_t)col*HH + 32 + quad*8));
    }

    // ---------------- decoder LDS views + init ----------------
    float* decB  = (float*)(uni + 0);      // 256 f
    float* attnB = (float*)(uni + 1024);   // 96 f
    float* embB  = (float*)(uni + 1408);   // 64 f
    float* combB = (float*)(uni + 1664);   // 64 f
    float* outB  = (float*)(uni + 1920);   // 8 f
    float* Lg    = (float*)(uni + 1952);   // [l][8b] logits
    u16t*  awB   = (u16t*)(uni + 5024);    // aw bf16 [b][96]
    u16t*  Ae    = (u16t*)(uni + 6560);    // emb A-buf
    u16t*  Ah0   = (u16t*)(uni + 8608);    // h A-buf ping
    u16t*  Ah1   = (u16t*)(uni + 10656);   // h A-buf pong
    u16t*  Actx  = (u16t*)(uni + 12704);   // ctx A-buf
    u16t*  Acmb  = (u16t*)(uni + 14752);   // comb A-buf
    u16t*  Apred = (u16t*)(uni + 16800);   // pred A-buf (K=32; k>=8 zero)

    #pragma unroll
    for (int rr = 0; rr < 2; ++rr){
        int b = (quad*4 + r0 + rr) & 7;
        Ah0[aaddr(jmy, b)]     = hb16[rr];
        Ah0[aaddr(jmy, b+8)]   = hb16[rr];
    }
    decB[tid] = ldf<F32>(dbih, tid) + ldf<F32>(dbhh, tid);
    if (tid < LL) attnB[tid] = ldf<F32>(attnb, tid);
    if (tid < HH) embB[tid]  = ldf<F32>(embb, tid);
    if (tid < HH) combB[tid] = ldf<F32>(combb, tid);
    if (tid < CC) outB[tid]  = ldf<F32>(outb, tid);
    for (int n = tid; n < 1024; n += 256) Apred[n] = 0;   // pred(0)=0 + K-pad
    __syncthreads();

    // eoG fragments for this wave's 2 batches -> registers
    const u16t* ebp = eoG + (size_t)(b0 + wv*2) * 6144;
    uint4 eF0[12], eF1[12];
    #pragma unroll
    for (int f = 0; f < 12; ++f) eF0[f] = *(const uint4*)(ebp + f*512 + quad*128 + col*8);
    #pragma unroll
    for (int f = 0; f < 12; ++f) eF1[f] = *(const uint4*)(ebp + 6144 + f*512 + quad*128 + col*8);

    const int lgS = tid & 31, bS = tid >> 5;
    const bf16x8* AeV   = (const bf16x8*)Ae;
    const bf16x8* ActxV = (const bf16x8*)Actx;
    const bf16x8* AcmbV = (const bf16x8*)Acmb;
    const bf16x8* ApV   = (const bf16x8*)Apred;

    for (int t = 0; t < TT; ++t){
        u16t* AhR = (t & 1) ? Ah1 : Ah0;
        u16t* AhW = (t & 1) ? Ah0 : Ah1;
        const bf16x8* AhV = (const bf16x8*)AhR;

        // P1: emb = relu(pred @ embW^T + b) via 1 MFMA/wave -> Ae (all rows)
        {
            bf16x8 ap = ApV[quad*16 + col];
            float eb = embB[wv*16 + col];
            f32x4 a; a[0]=eb; a[1]=eb; a[2]=eb; a[3]=eb;
            a = __builtin_amdgcn_mfma_f32_16x16x32_bf16(ap, eBf, a, 0,0,0);
            #pragma unroll
            for (int r = 0; r < 4; ++r)
                Ae[aaddr(wv*16+col, quad*4 + r)] = f2b(fmaxf(a[r], 0.f));
        }
        __syncthreads();

        // P2a: attention logits via MFMA -> Lg (rows 0-7 real)
        {
            bf16x8 ae0 = AeV[(0*4+quad)*16 + col], ae1 = AeV[(1*4+quad)*16 + col];
            bf16x8 ah0 = AhV[(0*4+quad)*16 + col], ah1 = AhV[(1*4+quad)*16 + col];
            const int ns = (wv < 2) ? 2 : 1;
            for (int s = 0; s < ns; ++s){
                int lt = (s == 0) ? wv : 4+wv;
                float bz = attnB[lt*16 + col];
                f32x4 a; a[0]=bz; a[1]=bz; a[2]=bz; a[3]=bz;
                a = __builtin_amdgcn_mfma_f32_16x16x32_bf16(ae0, Ba[s][0], a, 0,0,0);
                a = __builtin_amdgcn_mfma_f32_16x16x32_bf16(ae1, Ba[s][1], a, 0,0,0);
                a = __builtin_amdgcn_mfma_f32_16x16x32_bf16(ah0, Ba[s][2], a, 0,0,0);
                a = __builtin_amdgcn_mfma_f32_16x16x32_bf16(ah1, Ba[s][3], a, 0,0,0);
                if (quad < 2)
                    *(float4*)&Lg[(lt*16+col)*8 + quad*4] = make_float4(a[0],a[1],a[2],a[3]);
            }
        }
        __syncthreads();

        // P2b: softmax per batch -> awB (bf16, A-broadcast rows)
        {
            int l = lgS*3;
            float ev0 = Lg[l*8 + bS], ev1 = Lg[(l+1)*8 + bS], ev2 = Lg[(l+2)*8 + bS];
            float mx = fmaxf(ev0, fmaxf(ev1, ev2));
            #pragma unroll
            for (int m = 16; m >= 1; m >>= 1) mx = fmaxf(mx, __shfl_xor(mx, m, 32));
            float e0 = __expf(ev0 - mx), e1 = __expf(ev1 - mx), e2 = __expf(ev2 - mx);
            float sm = e0 + e1 + e2;
            #pragma unroll
            for (int m = 16; m >= 1; m >>= 1) sm += __shfl_xor(sm, m, 32);
            float inv = rcpf(sm);
            awB[bS*96 + l]     = f2b(e0*inv);
            awB[bS*96 + l + 1] = f2b(e1*inv);
            awB[bS*96 + l + 2] = f2b(e2*inv);
        }
        // P3: ctx via MFMA (A = aw broadcast, B = register eo frags); intra-wave
        // RAW on awB (same 32-lane group), no barrier.
        {
            const u16t* ap0 = awB + (wv*2)*96;
            bf16x8 f0 = *(const bf16x8*)(ap0 + quad*8);
            bf16x8 f1 = *(const bf16x8*)(ap0 + 32 + quad*8);
            bf16x8 f2 = *(const bf16x8*)(ap0 + 64 + quad*8);
            #pragma unroll
            for (int nt = 0; nt < 4; ++nt){
                f32x4 a; a[0]=0.f; a[1]=0.f; a[2]=0.f; a[3]=0.f;
                a = __builtin_amdgcn_mfma_f32_16x16x32_bf16(f0, u2b8(eF0[nt*3+0]), a, 0,0,0);
                a = __builtin_amdgcn_mfma_f32_16x16x32_bf16(f1, u2b8(eF0[nt*3+1]), a, 0,0,0);
                a = __builtin_amdgcn_mfma_f32_16x16x32_bf16(f2, u2b8(eF0[nt*3+2]), a, 0,0,0);
                if (quad == 0){
                    u16t v = f2b(a[0]);
                    Actx[aaddr(nt*16+col, wv*2)]   = v;
                    Actx[aaddr(nt*16+col, wv*2+8)] = v;
                }
            }
            const u16t* ap1 = awB + (wv*2+1)*96;
            bf16x8 g0 = *(const bf16x8*)(ap1 + quad*8);
            bf16x8 g1 = *(const bf16x8*)(ap1 + 32 + quad*8);
            bf16x8 g2 = *(const bf16x8*)(ap1 + 64 + quad*8);
            #pragma unroll
            for (int nt = 0; nt < 4; ++nt){
                f32x4 a; a[0]=0.f; a[1]=0.f; a[2]=0.f; a[3]=0.f;
                a = __builtin_amdgcn_mfma_f32_16x16x32_bf16(g0, u2b8(eF1[nt*3+0]), a, 0,0,0);
                a = __builtin_amdgcn_mfma_f32_16x16x32_bf16(g1, u2b8(eF1[nt*3+1]), a, 0,0,0);
                a = __builtin_amdgcn_mfma_f32_16x16x32_bf16(g2, u2b8(eF1[nt*3+2]), a, 0,0,0);
                if (quad == 0){
                    u16t v = f2b(a[0]);
                    Actx[aaddr(nt*16+col, wv*2+1)] = v;
                    Actx[aaddr(nt*16+col, wv*2+9)] = v;
                }
            }
        }
        __syncthreads();

        // P4: comb = [emb|ctx] @ combW^T + b via MFMA -> Acmb (all rows)
        {
            bf16x8 ae0 = AeV[(0*4+quad)*16 + col],   ae1 = AeV[(1*4+quad)*16 + col];
            bf16x8 ax0 = ActxV[(0*4+quad)*16 + col], ax1 = ActxV[(1*4+quad)*16 + col];
            float bz = combB[wv*16 + col];
            f32x4 a; a[0]=bz; a[1]=bz; a[2]=bz; a[3]=bz;
            a = __builtin_amdgcn_mfma_f32_16x16x32_bf16(ae0, Bc[0], a, 0,0,0);
            a = __builtin_amdgcn_mfma_f32_16x16x32_bf16(ae1, Bc[1], a, 0,0,0);
            a = __builtin_amdgcn_mfma_f32_16x16x32_bf16(ax0, Bc[2], a, 0,0,0);
            a = __builtin_amdgcn_mfma_f32_16x16x32_bf16(ax1, Bc[3], a, 0,0,0);
            #pragma unroll
            for (int r = 0; r < 4; ++r)
                Acmb[aaddr(wv*16+col, quad*4 + r)] = f2b(a[r]);
        }
        __syncthreads();

        // P5: dec LSTM gates via MFMA; all-lane 2-elem update; h -> AhW (+dup)
        {
            bf16x8 ac0 = AcmbV[(0*4+quad)*16 + col], ac1 = AcmbV[(1*4+quad)*16 + col];
            bf16x8 ah0 = AhV[(0*4+quad)*16 + col],   ah1 = AhV[(1*4+quad)*16 + col];
            f32x4 g4[4];
            #pragma unroll
            for (int g = 0; g < 4; ++g){
                float bz = decB[g*64 + wv*16 + col];
                f32x4 a; a[0]=bz; a[1]=bz; a[2]=bz; a[3]=bz;
                a = __builtin_amdgcn_mfma_f32_16x16x32_bf16(ac0, Bd[g][0], a, 0,0,0);
                a = __builtin_amdgcn_mfma_f32_16x16x32_bf16(ac1, Bd[g][1], a, 0,0,0);
                a = __builtin_amdgcn_mfma_f32_16x16x32_bf16(ah0, Bd[g][2], a, 0,0,0);
                a = __builtin_amdgcn_mfma_f32_16x16x32_bf16(ah1, Bd[g][3], a, 0,0,0);
                g4[g] = a;
            }
            #pragma unroll
            for (int rr = 0; rr < 2; ++rr){
                int r = r0 + rr;
                int b = (quad*4 + r) & 7;
                float c = sigm(g4[1][r])*creg[rr] + sigm(g4[0][r])*tanh2(g4[2][r]);
                float h = sigm(g4[3][r])*tanh2(c);
                creg[rr] = c;
                u16t hv = f2b(h);
                AhW[aaddr(jmy, b)]   = hv;
                AhW[aaddr(jmy, b+8)] = hv;
            }
        }
        __syncthreads();

        // P7: pred = h @ outW^T + b via 2 MFMA on wave 0 -> Apred (all rows) + outp
        if (wv == 0){
            const bf16x8* AhWV = (const bf16x8*)AhW;
            bf16x8 xh0 = AhWV[(0*4+quad)*16 + col];
            bf16x8 xh1 = AhWV[(1*4+quad)*16 + col];
            float ob = outB[col & 7];
            f32x4 a; a[0]=ob; a[1]=ob; a[2]=ob; a[3]=ob;
            a = __builtin_amdgcn_mfma_f32_16x16x32_bf16(xh0, oBf0, a, 0,0,0);
            a = __builtin_amdgcn_mfma_f32_16x16x32_bf16(xh1, oBf1, a, 0,0,0);
            if (col < CC){
                #pragma unroll
                for (int r = 0; r < 4; ++r){
                    int m = quad*4 + r, b = m & 7;
                    float p = a[r];
                    Apred[aaddr(col, m)] = f2b(p);
                    if (m < 8)
                        stf<F32>(outp, ((size_t)(b0+b)*TT + t)*CC + col, p + slp[col*10 + b]);
                }
            }
        }
        __syncthreads();
    }
}

// --------------------------------------------------------------- launch -----
extern "C" void kernel_launch(void* const* d_in, const int* in_sizes, int n_in,
                              void* d_out, int out_size, void* d_ws, size_t ws_size,
                              hipStream_t stream)
{
    (void)in_sizes; (void)n_in; (void)out_size; (void)ws_size;
    // ws_size >= 50.3 MB confirmed live in R8 (fused_g ran: LDS=25600 counters)
    fused_g<false><<<NB, 256, 0, stream>>>(
        d_in[0],
        d_in[4],  d_in[5],  d_in[6],  d_in[7],
        d_in[8],  d_in[9],  d_in[10], d_in[11],
        d_in[12], d_in[13], d_in[14], d_in[15],
        d_in[16], d_in[17], d_in[18], d_in[19],
        d_out, (u16t*)d_ws);
    fused_g<true><<<NB, 256, 0, stream>>>(
        d_in[0],
        d_in[4],  d_in[5],  d_in[6],  d_in[7],
        d_in[8],  d_in[9],  d_in[10], d_in[11],
        d_in[12], d_in[13], d_in[14], d_in[15],
        d_in[16], d_in[17], d_in[18], d_in[19],
        d_out, (u16t*)d_ws);
}